// Round 6
// baseline (132.970 us; speedup 1.0000x reference)
//
#include <hip/hip_runtime.h>

typedef unsigned short u16;
typedef unsigned int u32;
typedef short short8 __attribute__((ext_vector_type(8)));
typedef float f32x4 __attribute__((ext_vector_type(4)));

#define NTOK 1024
#define TT 16384   // N*B*L tokens
#define DD 128
#define EPSV 1e-5f
#define ST 2097152 // TT*DD, elements per expert-slice

__device__ __forceinline__ u16 f2bf(float f) {
    u32 u = __float_as_uint(f);
    u += 0x7fffu + ((u >> 16) & 1u);
    return (u16)(u >> 16);
}
__device__ __forceinline__ u32 pack2(u16 a, u16 b) { return (u32)a | ((u32)b << 16); }
// cheap bf16-pair unpack: 1 VALU per element
__device__ __forceinline__ void up2(u32 w, float& lo, float& hi) {
    lo = __uint_as_float(w << 16);
    hi = __uint_as_float(w & 0xffff0000u);
}
__device__ __forceinline__ float rfl_f(float v) {
    return __uint_as_float(__builtin_amdgcn_readfirstlane(__float_as_uint(v)));
}

// ---------------- fused prep: x->bf16 | weights->bf16 | router logits ----------------
// blocks [0,1024): cvt x ; [1024,1344): cvt weights ; [1344,1360): logits
__global__ __launch_bounds__(256) void k_prep(const float* __restrict__ x,
        const float* __restrict__ eWq, const float* __restrict__ eWk,
        const float* __restrict__ eWv, const float* __restrict__ eWo, const float* __restrict__ eW1,
        const float* __restrict__ mWq, const float* __restrict__ mWk, const float* __restrict__ mWv,
        const float* __restrict__ mWo, const float* __restrict__ mW2,
        const float* __restrict__ mm, const float* __restrict__ Wr, const float* __restrict__ br,
        u16* __restrict__ Xb, u16* __restrict__ Wb, float* __restrict__ logits) {
    int bid = blockIdx.x; int tid = threadIdx.x;
    if (bid < 1024) {
        int i = bid * 256 + tid;
        const float4* p = (const float4*)x + (size_t)i * 2;
        float4 a = p[0], b = p[1];
        uint4 o;
        o.x = pack2(f2bf(a.x), f2bf(a.y));
        o.y = pack2(f2bf(a.z), f2bf(a.w));
        o.z = pack2(f2bf(b.x), f2bf(b.y));
        o.w = pack2(f2bf(b.z), f2bf(b.w));
        *((uint4*)Xb + i) = o;
    } else if (bid < 1344) {
        int i = (bid - 1024) * 256 + tid;     // 81920 threads, 8 elems each
        int tns = i >> 13;
        int off = (i & 8191) * 8;
        const float* src;
        switch (tns) {
            case 0: src = eWq; break; case 1: src = eWk; break; case 2: src = eWv; break;
            case 3: src = eWo; break; case 4: src = eW1; break; case 5: src = mWq; break;
            case 6: src = mWk; break; case 7: src = mWv; break; case 8: src = mWo; break;
            default: src = mW2; break;
        }
        const float4* p = (const float4*)(src + off);
        float4 a = p[0], b = p[1];
        uint4 o;
        o.x = pack2(f2bf(a.x), f2bf(a.y));
        o.y = pack2(f2bf(a.z), f2bf(a.w));
        o.z = pack2(f2bf(b.x), f2bf(b.y));
        o.w = pack2(f2bf(b.z), f2bf(b.w));
        *(uint4*)(Wb + tns * 65536 + off) = o;
    } else {
        int i = (bid - 1344) * 256 + tid;     // 4096 = 1024 n * 4 e
        int n = i >> 2, e = i & 3;
        const float4* a = (const float4*)(mm + (size_t)n * DD);
        const float4* w = (const float4*)(Wr + (size_t)e * DD);
        float s = 0.f;
#pragma unroll
        for (int j = 0; j < 32; j++) {
            float4 av = a[j], wv = w[j];
            s += av.x * wv.x + av.y * wv.y + av.z * wv.z + av.w * wv.w;
        }
        logits[i] = s + br[e];
    }
}

// ---------------- routing: softmax, top2, capacity (ballot scan), masks, loss, zero stats ---
__global__ __launch_bounds__(1024) void k_route(const float* __restrict__ logits, const int* __restrict__ modix,
                                                float* __restrict__ mask8, float* __restrict__ comb8,
                                                float* __restrict__ cnt8, float* __restrict__ bnsum,
                                                float* __restrict__ bnsq, float* __restrict__ loss) {
    __shared__ int wsum[4][16];
    __shared__ float red[16];
    int n = threadIdx.x;
    if (n < 16) red[n] = 0.f;
    bnsum[n] = 0.f; bnsq[n] = 0.f;                      // zero [8][128] stats
    float g[4];
    float mx = -1e30f;
#pragma unroll
    for (int e = 0; e < 4; e++) { g[e] = logits[n * 4 + e]; mx = fmaxf(mx, g[e]); }
    float s = 0.f;
#pragma unroll
    for (int e = 0; e < 4; e++) { g[e] = expf(g[e] - mx); s += g[e]; }
    float inv = 1.f / s;
#pragma unroll
    for (int e = 0; e < 4; e++) g[e] *= inv;
    // top2 of gate (ties -> lower index, matching lax.top_k)
    int i0 = 0; float b0 = g[0];
#pragma unroll
    for (int e = 1; e < 4; e++) if (g[e] > b0) { b0 = g[e]; i0 = e; }
    int i1 = -1; float b1v = -1e30f;
#pragma unroll
    for (int e = 0; e < 4; e++) if (e != i0 && g[e] > b1v) { b1v = g[e]; i1 = e; }
    u32 rbits = (1u << i0) | (1u << i1);
    // inclusive cumsum per expert via wave ballot + cross-wave scan; keep iff <= N/E = 256
    int wav = n >> 6, lane = n & 63;
    unsigned long long lm = (~0ull) >> (63 - lane);     // bits 0..lane
    int pre[4];
#pragma unroll
    for (int e = 0; e < 4; e++) {
        unsigned long long m = __ballot((rbits >> e) & 1u);
        pre[e] = __popcll(m & lm);
        if (lane == 63) wsum[e][wav] = __popcll(m);
    }
    __syncthreads();
    float rp[4]; float rsum = 0.f;
#pragma unroll
    for (int e = 0; e < 4; e++) {
        int off = 0;
        for (int w = 0; w < 16; w++) if (w < wav) off += wsum[e][w];
        bool keep = (off + pre[e]) <= 256;
        rp[e] = (((rbits >> e) & 1u) && keep) ? g[e] : 0.f;
        rsum += rp[e];
    }
    bool active = rsum > 0.f;
    // top2 of rprobs (reproduce lax.top_k filler-index tie-break for the BN mask)
    int j0 = 0; float c0 = rp[0];
#pragma unroll
    for (int e = 1; e < 4; e++) if (rp[e] > c0) { c0 = rp[e]; j0 = e; }
    int j1 = -1; float c1 = -1e30f;
#pragma unroll
    for (int e = 0; e < 4; e++) if (e != j0 && rp[e] > c1) { c1 = rp[e]; j1 = e; }
    float vals[16];
#pragma unroll
    for (int e = 0; e < 4; e++) {
        bool sel = active && (e == j0 || e == j1);
        float mf = sel ? 1.f : 0.f;
        mask8[e * NTOK + n] = mf;
        comb8[e * NTOK + n] = rp[e];
        vals[e] = mf;
    }
#pragma unroll
    for (int m = 0; m < 4; m++) {
        float mf = (modix[n * 4 + m] == 1) ? 1.f : 0.f;
        mask8[(4 + m) * NTOK + n] = mf;
        comb8[(4 + m) * NTOK + n] = 0.25f * mf;         // mod_out / Mn folded in
        vals[4 + m] = mf;
    }
#pragma unroll
    for (int e = 0; e < 4; e++) vals[8 + e] = ((rbits >> e) & 1u) ? 1.f : 0.f;
#pragma unroll
    for (int e = 0; e < 4; e++) vals[12 + e] = g[e];
#pragma unroll
    for (int q = 0; q < 16; q++) {
        float v = vals[q];
        for (int off = 32; off; off >>= 1) v += __shfl_down(v, off, 64);
        if (lane == 0) atomicAdd(&red[q], v);
    }
    __syncthreads();
    if (n == 0) {
        for (int c = 0; c < 8; c++) cnt8[c] = fmaxf(16.f * red[c], 1.f);
        float l = 0.f;
        for (int e = 0; e < 4; e++) l += (red[8 + e] / 1024.f) * (red[12 + e] / 1024.f);
        loss[0] = 4.f * l;
    }
}

// ---------------- batched QKV projection: grid (256 bm, 8 c), bf16 weights, Q mask-skip ----
__global__ __launch_bounds__(256) void k_gemm_qkv(const u16* __restrict__ Xb, const u16* __restrict__ Wb,
        const float* __restrict__ ebq, const float* __restrict__ mbq,
        const float* __restrict__ mask8,
        u16* __restrict__ Qb, u16* __restrict__ Kb, u16* __restrict__ Vb) {
    __shared__ u16 As[64 * 128];
    __shared__ u16 Bs[128 * 128];
    int tid = threadIdx.x; int bm = blockIdx.x; int c = blockIdx.y;
    int wq = (c < 4) ? c : 20 + (c - 4);
    int wk = (c < 4) ? 4 + c : 24 + (c - 4);
    int wv = (c < 4) ? 8 + c : 28 + (c - 4);
    const u16* Wsl[3] = { Wb + wq * 16384, Wb + wk * 16384, Wb + wv * 16384 };
    const float* bq = (c < 4) ? (ebq + c * 128) : (mbq + (c - 4) * 128);
    u16* Os[3] = { Qb + (size_t)c * ST, Kb + (size_t)c * ST, Vb + (size_t)c * ST };
    const float* maskp = mask8 + c * NTOK;
    bool qact = (maskp[bm * 4] != 0.f) || (maskp[bm * 4 + 1] != 0.f) ||
                (maskp[bm * 4 + 2] != 0.f) || (maskp[bm * 4 + 3] != 0.f);

    const uint4* asrc = (const uint4*)(Xb + (size_t)bm * 8192);
#pragma unroll
    for (int it = 0; it < 4; ++it) {
        int ci = it * 256 + tid;
        uint4 v = asrc[ci];
        int byte = ci * 16; int row = byte >> 8;
        *(uint4*)((char*)As + (byte ^ ((row & 7) << 4))) = v;
    }
    __syncthreads();
    int lane = tid & 63, wid = tid >> 6, lr = lane & 15, lg = lane >> 4;
    short8 a[4];
#pragma unroll
    for (int ks = 0; ks < 4; ++ks) {
        int kk = ks * 64 + lg * 16;
        int arow = wid * 16 + lr;
        a[ks] = *(const short8*)((const char*)As + ((arow * 256 + kk) ^ ((arow & 7) << 4)));
    }
    for (int y = 0; y < 3; ++y) {
        if (y == 0 && !qact) continue;   // Q only read for masked tokens (block-uniform skip)
        const uint4* wsrc = (const uint4*)Wsl[y];
#pragma unroll
        for (int it = 0; it < 8; ++it) {
            int qi = it * 256 + tid;
            uint4 v = wsrc[qi];
            int eo = qi * 8; int row = eo >> 7; int byte = eo * 2;
            *(uint4*)((char*)Bs + (byte ^ ((row & 7) << 4))) = v;
        }
        __syncthreads();
        f32x4 acc[8] = {};
#pragma unroll
        for (int ks = 0; ks < 4; ++ks) {
            int kk = ks * 64 + lg * 16;
#pragma unroll
            for (int nc = 0; nc < 8; ++nc) {
                int brow = nc * 16 + lr;
                short8 b = *(const short8*)((const char*)Bs + ((brow * 256 + kk) ^ ((brow & 7) << 4)));
                acc[nc] = __builtin_amdgcn_mfma_f32_16x16x32_bf16(a[ks], b, acc[nc], 0, 0, 0);
            }
        }
        int row0 = bm * 64 + wid * 16 + lg * 4;
        u16* Op = Os[y];
        bool hasb = (y == 0);
#pragma unroll
        for (int nc = 0; nc < 8; ++nc) {
            int col = nc * 16 + lr;
            float bb = hasb ? bq[col] : 0.f;
#pragma unroll
            for (int r = 0; r < 4; r++)
                Op[(size_t)(row0 + r) * 128 + col] = f2bf(acc[nc][r] + bb);
        }
        __syncthreads();
    }
}

// ---------------- MERGED gather-attention + O@Wo^T + masked BN stats --------------------
// grid 2048 linear, c = bid&7 (XCD pin), bm = bid>>3; 512 threads (8 waves).
// Attention result goes straight into the swizzled LDS A-tile; then MFMA; then O2+stats.
__global__ __launch_bounds__(512) void k_attn_o(const u16* __restrict__ Qb, const u16* __restrict__ Kb,
        const u16* __restrict__ Vb, const float* __restrict__ tkv, const int* __restrict__ idx,
        const float* __restrict__ ebk, const float* __restrict__ ebv,
        const float* __restrict__ mbk, const float* __restrict__ mbv,
        const u16* __restrict__ Wb, const float* __restrict__ ebo, const float* __restrict__ mbo,
        const float* __restrict__ mask8, u16* __restrict__ O2,
        float* __restrict__ bnsum, float* __restrict__ bnsq) {
    __shared__ u16 As[64 * 128];
    __shared__ u16 Bs[128 * 128];
    __shared__ float ssum[128], ssq[128];
    int bid = blockIdx.x;
    int c = bid & 7, bm = bid >> 3;
    const float* maskp = mask8 + c * NTOK;
    float m4[4];
    m4[0] = maskp[bm * 4];     m4[1] = maskp[bm * 4 + 1];
    m4[2] = maskp[bm * 4 + 2]; m4[3] = maskp[bm * 4 + 3];
    if (m4[0] == 0.f && m4[1] == 0.f && m4[2] == 0.f && m4[3] == 0.f) return;
    int tid = threadIdx.x;
    if (tid < 128) { ssum[tid] = 0.f; ssq[tid] = 0.f; }
    // early-issue Wo B-tile loads (latency hides under the gather)
    int wo = (c < 4) ? 12 + c : 32 + (c - 4);
    const uint4* wsrc = (const uint4*)(Wb + wo * 16384);
    uint4 bst[4];
#pragma unroll
    for (int it = 0; it < 4; ++it) bst[it] = wsrc[it * 512 + tid];

    // ---- attention phase: thread = (tl, h); wave-uniform n ----
    int tl = tid >> 3, h = tid & 7;
    int nl = tl >> 4;
    int n = bm * 4 + nl;
    float mk_n = m4[nl];            // wave-uniform
    int b0 = tl * 256 + h * 32;     // byte pos of this thread's 32B in the A-tile row
    int sw = (tl & 7) << 4;
    if (mk_n != 0.f) {
        const u16* Qc = Qb + (size_t)c * ST;
        const u16* Kc = Kb + (size_t)c * ST;
        const u16* Vc = Vb + (size_t)c * ST;
        const float* bk = (c < 4) ? (ebk + c * 128) : (mbk + (c - 4) * 128);
        const float* bv = (c < 4) ? (ebv + c * 128) : (mbv + (c - 4) * 128);
        int t = bm * 64 + tl;
        int bl = tl & 15;
        float qv[16];
        {
            const uint4* qp = (const uint4*)(Qc + (size_t)t * 128 + h * 16);
            uint4 a = qp[0], b = qp[1];
            up2(a.x, qv[0], qv[1]);   up2(a.y, qv[2], qv[3]);
            up2(a.z, qv[4], qv[5]);   up2(a.w, qv[6], qv[7]);
            up2(b.x, qv[8], qv[9]);   up2(b.y, qv[10], qv[11]);
            up2(b.z, qv[12], qv[13]); up2(b.w, qv[14], qv[15]);
        }
        float qb = 0.f;
#pragma unroll
        for (int i = 0; i < 16; i++) qb += qv[i] * bk[h * 16 + i];
        int gsav[16]; float tsav[16];
#pragma unroll
        for (int k = 0; k < 16; k++) {
            gsav[k] = __builtin_amdgcn_readfirstlane(idx[n * 16 + k]);
            tsav[k] = rfl_f(tkv[n * 16 + k]);
        }
        float scv[16]; float smax = -1e30f;
#pragma unroll 2
        for (int k = 0; k < 16; k++) {
            const uint4* kp = (const uint4*)(Kc + (size_t)(gsav[k] * 16 + bl) * 128 + h * 16);
            uint4 a = kp[0], b = kp[1];
            float d0 = 0.f, d1 = 0.f, lo, hi;
            up2(a.x, lo, hi); d0 = fmaf(lo, qv[0], d0);  d1 = fmaf(hi, qv[1], d1);
            up2(a.y, lo, hi); d0 = fmaf(lo, qv[2], d0);  d1 = fmaf(hi, qv[3], d1);
            up2(a.z, lo, hi); d0 = fmaf(lo, qv[4], d0);  d1 = fmaf(hi, qv[5], d1);
            up2(a.w, lo, hi); d0 = fmaf(lo, qv[6], d0);  d1 = fmaf(hi, qv[7], d1);
            up2(b.x, lo, hi); d0 = fmaf(lo, qv[8], d0);  d1 = fmaf(hi, qv[9], d1);
            up2(b.y, lo, hi); d0 = fmaf(lo, qv[10], d0); d1 = fmaf(hi, qv[11], d1);
            up2(b.z, lo, hi); d0 = fmaf(lo, qv[12], d0); d1 = fmaf(hi, qv[13], d1);
            up2(b.w, lo, hi); d0 = fmaf(lo, qv[14], d0); d1 = fmaf(hi, qv[15], d1);
            float sv = 0.25f * (tsav[k] * (d0 + d1) + qb);   // k = tkv*kx + bk ; 1/sqrt(dh)=0.25
            scv[k] = sv; smax = fmaxf(smax, sv);
        }
        float sum = 0.f;
#pragma unroll
        for (int k = 0; k < 16; k++) { scv[k] = __expf(scv[k] - smax); sum += scv[k]; }
        float inv = 1.f / sum;
        float o[16];
#pragma unroll
        for (int i = 0; i < 16; i++) o[i] = 0.f;
#pragma unroll 2
        for (int k = 0; k < 16; k++) {
            const uint4* vp = (const uint4*)(Vc + (size_t)(gsav[k] * 16 + bl) * 128 + h * 16);
            uint4 a = vp[0], b = vp[1];
            float cc = scv[k] * inv * tsav[k];
            float lo, hi;
            up2(a.x, lo, hi); o[0] = fmaf(lo, cc, o[0]);   o[1] = fmaf(hi, cc, o[1]);
            up2(a.y, lo, hi); o[2] = fmaf(lo, cc, o[2]);   o[3] = fmaf(hi, cc, o[3]);
            up2(a.z, lo, hi); o[4] = fmaf(lo, cc, o[4]);   o[5] = fmaf(hi, cc, o[5]);
            up2(a.w, lo, hi); o[6] = fmaf(lo, cc, o[6]);   o[7] = fmaf(hi, cc, o[7]);
            up2(b.x, lo, hi); o[8] = fmaf(lo, cc, o[8]);   o[9] = fmaf(hi, cc, o[9]);
            up2(b.y, lo, hi); o[10] = fmaf(lo, cc, o[10]); o[11] = fmaf(hi, cc, o[11]);
            up2(b.z, lo, hi); o[12] = fmaf(lo, cc, o[12]); o[13] = fmaf(hi, cc, o[13]);
            up2(b.w, lo, hi); o[14] = fmaf(lo, cc, o[14]); o[15] = fmaf(hi, cc, o[15]);
        }
#pragma unroll
        for (int i = 0; i < 16; i++) o[i] += bv[h * 16 + i];   // sum(attn)=1
        uint4 s0, s1;
        s0.x = pack2(f2bf(o[0]), f2bf(o[1]));  s0.y = pack2(f2bf(o[2]), f2bf(o[3]));
        s0.z = pack2(f2bf(o[4]), f2bf(o[5]));  s0.w = pack2(f2bf(o[6]), f2bf(o[7]));
        s1.x = pack2(f2bf(o[8]), f2bf(o[9]));  s1.y = pack2(f2bf(o[10]), f2bf(o[11]));
        s1.z = pack2(f2bf(o[12]), f2bf(o[13])); s1.w = pack2(f2bf(o[14]), f2bf(o[15]));
        *(uint4*)((char*)As + (b0 ^ sw)) = s0;
        *(uint4*)((char*)As + ((b0 + 16) ^ sw)) = s1;
    } else {
        uint4 z = {0u, 0u, 0u, 0u};     // zero rows: keep MFMA finite (stats are x0 anyway)
        *(uint4*)((char*)As + (b0 ^ sw)) = z;
        *(uint4*)((char*)As + ((b0 + 16) ^ sw)) = z;
    }
    // store early-loaded Wo tile into swizzled Bs
#pragma unroll
    for (int it = 0; it < 4; ++it) {
        int qi = it * 512 + tid;
        int eo = qi * 8; int row = eo >> 7; int byte = eo * 2;
        *(uint4*)((char*)Bs + (byte ^ ((row & 7) << 4))) = bst[it];
    }
    __syncthreads();
    // ---- MFMA phase: 8 waves, wm = m-frag, wn = n-half ----
    int lane = tid & 63, wid = tid >> 6, lr = lane & 15, lg = lane >> 4;
    int wm = wid & 3, wn = wid >> 2;
    f32x4 acc[4] = {};
#pragma unroll
    for (int ks = 0; ks < 4; ++ks) {
        int kk = ks * 64 + lg * 16;
        int arow = wm * 16 + lr;
        short8 a = *(const short8*)((const char*)As + ((arow * 256 + kk) ^ ((arow & 7) << 4)));
#pragma unroll
        for (int nc = 0; nc < 4; ++nc) {
            int brow = wn * 64 + nc * 16 + lr;
            short8 b = *(const short8*)((const char*)Bs + ((brow * 256 + kk) ^ ((brow & 7) << 4)));
            acc[nc] = __builtin_amdgcn_mfma_f32_16x16x32_bf16(a, b, acc[nc], 0, 0, 0);
        }
    }
    const float* bo = (c < 4) ? (ebo + c * 128) : (mbo + (c - 4) * 128);
    float mk = m4[wm];
    int row0 = bm * 64 + wm * 16 + lg * 4;
    u16* O2c = O2 + (size_t)c * ST;
    float ps[4], pq[4];
#pragma unroll
    for (int nc = 0; nc < 4; ++nc) {
        int col = wn * 64 + nc * 16 + lr;
        float bb = bo[col];
        float sv = 0.f, qv = 0.f;
#pragma unroll
        for (int r = 0; r < 4; r++) {
            float v = acc[nc][r] + bb;
            if (mk != 0.f) O2c[(size_t)(row0 + r) * 128 + col] = f2bf(v);
            sv += v; qv += v * v;
        }
        ps[nc] = sv * mk; pq[nc] = qv * mk;
    }
#pragma unroll
    for (int nc = 0; nc < 4; ++nc) {
        ps[nc] += __shfl_xor(ps[nc], 16, 64); ps[nc] += __shfl_xor(ps[nc], 32, 64);
        pq[nc] += __shfl_xor(pq[nc], 16, 64); pq[nc] += __shfl_xor(pq[nc], 32, 64);
    }
    if (lane < 16) {
#pragma unroll
        for (int nc = 0; nc < 4; ++nc) {
            atomicAdd(&ssum[wn * 64 + nc * 16 + lane], ps[nc]);
            atomicAdd(&ssq[wn * 64 + nc * 16 + lane], pq[nc]);
        }
    }
    __syncthreads();
    if (tid < 128) { atomicAdd(&bnsum[c * 128 + tid], ssum[tid]); atomicAdd(&bnsq[c * 128 + tid], ssq[tid]); }
}

// ---------------- fused final GEMM over 8 experts, 512 threads (8 waves): grid 256 ----------
__global__ __launch_bounds__(512) void k_gemm_w1(const u16* __restrict__ O2, const u16* __restrict__ Xb,
        const u16* __restrict__ Wb, const float* __restrict__ eb1, const float* __restrict__ mb2,
        const float* __restrict__ eGamma, const float* __restrict__ mGamma,
        const float* __restrict__ eBeta, const float* __restrict__ mBeta,
        const float* __restrict__ comb8, const float* __restrict__ cnt8,
        const float* __restrict__ bnsum, const float* __restrict__ bnsq,
        float* __restrict__ out) {
    __shared__ u16 As[64 * 128];
    __shared__ u16 Bs[128 * 128];
    __shared__ float scall[8][128], shall[8][128];
    int tid = threadIdx.x; int bm = blockIdx.x;
    // BN scale/shift for all 8 experts
#pragma unroll
    for (int j = 0; j < 2; ++j) {
        int id = j * 512 + tid;
        int c = id >> 7, d = id & 127;
        float cnt = cnt8[c];
        float mean = bnsum[c * 128 + d] / cnt;
        float var = bnsq[c * 128 + d] / cnt - mean * mean;
        float rs = rsqrtf(var + EPSV);
        const float* ga = (c < 4) ? (eGamma + c * 128) : (mGamma + (c - 4) * 128);
        const float* be = (c < 4) ? (eBeta + c * 128) : (mBeta + (c - 4) * 128);
        float gg = ga[d];
        scall[c][d] = rs * gg;
        shall[c][d] = be[d] - mean * rs * gg;
    }
    __syncthreads();
    int lane = tid & 63, wid = tid >> 6, lr = lane & 15, lg = lane >> 4;
    int wm = wid & 3, wn = wid >> 2;        // 4 m-frags x 2 n-halves
    f32x4 acc[4] = {};
    const uint4* xsrc = (const uint4*)(Xb + (size_t)bm * 8192);
    for (int c = 0; c < 8; ++c) {
        float wc4[4];
        wc4[0] = comb8[c * NTOK + bm * 4];     wc4[1] = comb8[c * NTOK + bm * 4 + 1];
        wc4[2] = comb8[c * NTOK + bm * 4 + 2]; wc4[3] = comb8[c * NTOK + bm * 4 + 3];
        if (wc4[0] == 0.f && wc4[1] == 0.f && wc4[2] == 0.f && wc4[3] == 0.f) continue;
        int wsl = (c < 4) ? 16 + c : 36 + (c - 4);
        const u16* Wp = Wb + wsl * 16384;
        const uint4* osrc = (const uint4*)(O2 + (size_t)c * ST + (size_t)bm * 8192);
        // stage A = wc * (BN(O2) + x), bf16
#pragma unroll
        for (int it = 0; it < 2; ++it) {
            int qi = it * 512 + tid;
            int eo = qi * 8; int row = eo >> 7; int cb = eo & 127;
            float wc = wc4[row >> 4];
            uint4 ov = osrc[qi]; uint4 xv = xsrc[qi];
            float olo, ohi, xlo, xhi;
            uint4 hh;
            up2(ov.x, olo, ohi); up2(xv.x, xlo, xhi);
            hh.x = pack2(f2bf((olo * scall[c][cb] + shall[c][cb] + xlo) * wc),
                         f2bf((ohi * scall[c][cb + 1] + shall[c][cb + 1] + xhi) * wc));
            up2(ov.y, olo, ohi); up2(xv.y, xlo, xhi);
            hh.y = pack2(f2bf((olo * scall[c][cb + 2] + shall[c][cb + 2] + xlo) * wc),
                         f2bf((ohi * scall[c][cb + 3] + shall[c][cb + 3] + xhi) * wc));
            up2(ov.z, olo, ohi); up2(xv.z, xlo, xhi);
            hh.z = pack2(f2bf((olo * scall[c][cb + 4] + shall[c][cb + 4] + xlo) * wc),
                         f2bf((ohi * scall[c][cb + 5] + shall[c][cb + 5] + xhi) * wc));
            up2(ov.w, olo, ohi); up2(xv.w, xlo, xhi);
            hh.w = pack2(f2bf((olo * scall[c][cb + 6] + shall[c][cb + 6] + xlo) * wc),
                         f2bf((ohi * scall[c][cb + 7] + shall[c][cb + 7] + xhi) * wc));
            *(uint4*)((char*)As + ((eo * 2) ^ ((row & 7) << 4))) = hh;
        }
        const uint4* wsrc = (const uint4*)Wp;
#pragma unroll
        for (int it = 0; it < 4; ++it) {
            int qi = it * 512 + tid;
            uint4 v = wsrc[qi];
            int eo = qi * 8; int row = eo >> 7; int byte = eo * 2;
            *(uint4*)((char*)Bs + (byte ^ ((row & 7) << 4))) = v;
        }
        __syncthreads();
#pragma unroll
        for (int ks = 0; ks < 4; ++ks) {
            int kk = ks * 64 + lg * 16;
            int arow = wm * 16 + lr;
            short8 a = *(const short8*)((const char*)As + ((arow * 256 + kk) ^ ((arow & 7) << 4)));
#pragma unroll
            for (int nc = 0; nc < 4; ++nc) {
                int brow = wn * 64 + nc * 16 + lr;
                short8 b = *(const short8*)((const char*)Bs + ((brow * 256 + kk) ^ ((brow & 7) << 4)));
                acc[nc] = __builtin_amdgcn_mfma_f32_16x16x32_bf16(a, b, acc[nc], 0, 0, 0);
            }
        }
        __syncthreads();
    }
    // epilogue: add Sum_c wc*b1_c and write out once
    int nidx = bm * 4 + wm;
    int row0 = bm * 64 + wm * 16 + lg * 4;
    float wc8[8];
#pragma unroll
    for (int c = 0; c < 8; ++c) wc8[c] = comb8[c * NTOK + nidx];
#pragma unroll
    for (int nc = 0; nc < 4; ++nc) {
        int col = wn * 64 + nc * 16 + lr;
        float bias = 0.f;
#pragma unroll
        for (int c = 0; c < 8; ++c) {
            const float* b1 = (c < 4) ? (eb1 + c * 128) : (mb2 + (c - 4) * 128);
            bias += wc8[c] * b1[col];
        }
#pragma unroll
        for (int r = 0; r < 4; r++)
            out[(size_t)(row0 + r) * 128 + col] = acc[nc][r] + bias;
    }
}

extern "C" void kernel_launch(void* const* d_in, const int* in_sizes, int n_in,
                              void* d_out, int out_size, void* d_ws, size_t ws_size,
                              hipStream_t stream) {
    (void)in_sizes; (void)n_in; (void)ws_size; (void)out_size;
    const float* x    = (const float*)d_in[0];
    const float* mm   = (const float*)d_in[1];
    const float* tkv  = (const float*)d_in[2];
    const int*   idx  = (const int*)d_in[3];
    const int*   modi = (const int*)d_in[4];
    const float* Wr   = (const float*)d_in[5];
    const float* br   = (const float*)d_in[6];
    const float* eWq = (const float*)d_in[7],  *eWk = (const float*)d_in[8],  *eWv = (const float*)d_in[9];
    const float* eWo = (const float*)d_in[10], *eW1 = (const float*)d_in[11];
    const float* mWq = (const float*)d_in[12], *mWk = (const float*)d_in[13], *mWv = (const float*)d_in[14];
    const float* mWo = (const float*)d_in[15], *mW2 = (const float*)d_in[16];
    const float* ebq = (const float*)d_in[17], *ebk = (const float*)d_in[18], *ebv = (const float*)d_in[19];
    const float* ebo = (const float*)d_in[20], *eBeta = (const float*)d_in[21], *eb1 = (const float*)d_in[22];
    const float* mbq = (const float*)d_in[23], *mbk = (const float*)d_in[24], *mbv = (const float*)d_in[25];
    const float* mbo = (const float*)d_in[26], *mBeta = (const float*)d_in[27], *mb2 = (const float*)d_in[28];
    const float* eGamma = (const float*)d_in[29], *mGamma = (const float*)d_in[30];
    float* out = (float*)d_out;

    char* wsb = (char*)d_ws;
    const size_t MB = 1024 * 1024;
    u16* Xb = (u16*)wsb;                        // 0..4 MB
    u16* Wb = (u16*)(wsb + 4 * MB);             // 4..5.3 MB (40 x 16384 bf16)
    u16* Qb = (u16*)(wsb + 8 * MB);             // 8..40 MB
    u16* Kb = (u16*)(wsb + 40 * MB);            // 40..72 MB
    u16* Vb = (u16*)(wsb + 72 * MB);            // 72..104 MB
    u16* O2 = (u16*)(wsb + 104 * MB);           // 104..136 MB (bf16)
    float* logits = (float*)(wsb + 136 * MB);
    float* comb8 = logits + 4096;               // [8][1024]
    float* mask8 = comb8 + 8192;                // [8][1024]
    float* cnt8  = mask8 + 8192;                // [8]
    float* bnsum = cnt8 + 16;                   // [8][128]
    float* bnsq  = bnsum + 1024;                // [8][128]

    k_prep<<<1360, 256, 0, stream>>>(x, eWq, eWk, eWv, eWo, eW1, mWq, mWk, mWv, mWo, mW2,
                                     mm, Wr, br, Xb, Wb, logits);
    k_route<<<1, 1024, 0, stream>>>(logits, modi, mask8, comb8, cnt8, bnsum, bnsq,
                                    out + (size_t)TT * DD);
    k_gemm_qkv<<<dim3(256, 8), 256, 0, stream>>>(Xb, Wb, ebq, mbq, mask8, Qb, Kb, Vb);
    k_attn_o<<<2048, 512, 0, stream>>>(Qb, Kb, Vb, tkv, idx, ebk, ebv, mbk, mbv,
                                       Wb, ebo, mbo, mask8, O2, bnsum, bnsq);
    k_gemm_w1<<<256, 512, 0, stream>>>(O2, Xb, Wb, eb1, mb2, eGamma, mGamma, eBeta, mBeta,
                                       comb8, cnt8, bnsum, bnsq, out);
}

// Round 8
// 125.022 us; speedup vs baseline: 1.0636x; 1.0636x over previous
//
#include <hip/hip_runtime.h>

typedef unsigned short u16;
typedef unsigned int u32;
typedef short short8 __attribute__((ext_vector_type(8)));
typedef float f32x4 __attribute__((ext_vector_type(4)));

#define NTOK 1024
#define TT 16384   // N*B*L tokens
#define DD 128
#define EPSV 1e-5f
#define ST 2097152 // TT*DD, elements per expert-slice

__device__ __forceinline__ u16 f2bf(float f) {
    u32 u = __float_as_uint(f);
    u += 0x7fffu + ((u >> 16) & 1u);
    return (u16)(u >> 16);
}
__device__ __forceinline__ u32 pack2(u16 a, u16 b) { return (u32)a | ((u32)b << 16); }
// cheap bf16-pair unpack: 1 VALU per element
__device__ __forceinline__ void up2(u32 w, float& lo, float& hi) {
    lo = __uint_as_float(w << 16);
    hi = __uint_as_float(w & 0xffff0000u);
}

// ---------------- fused prep: x->bf16 | weights->bf16 | router logits ----------------
// blocks [0,1024): cvt x ; [1024,1344): cvt weights ; [1344,1360): logits
__global__ __launch_bounds__(256) void k_prep(const float* __restrict__ x,
        const float* __restrict__ eWq, const float* __restrict__ eWk,
        const float* __restrict__ eWv, const float* __restrict__ eWo, const float* __restrict__ eW1,
        const float* __restrict__ mWq, const float* __restrict__ mWk, const float* __restrict__ mWv,
        const float* __restrict__ mWo, const float* __restrict__ mW2,
        const float* __restrict__ mm, const float* __restrict__ Wr, const float* __restrict__ br,
        u16* __restrict__ Xb, u16* __restrict__ Wb, float* __restrict__ logits) {
    int bid = blockIdx.x; int tid = threadIdx.x;
    if (bid < 1024) {
        int i = bid * 256 + tid;
        const float4* p = (const float4*)x + (size_t)i * 2;
        float4 a = p[0], b = p[1];
        uint4 o;
        o.x = pack2(f2bf(a.x), f2bf(a.y));
        o.y = pack2(f2bf(a.z), f2bf(a.w));
        o.z = pack2(f2bf(b.x), f2bf(b.y));
        o.w = pack2(f2bf(b.z), f2bf(b.w));
        *((uint4*)Xb + i) = o;
    } else if (bid < 1344) {
        int i = (bid - 1024) * 256 + tid;     // 81920 threads, 8 elems each
        int tns = i >> 13;
        int off = (i & 8191) * 8;
        const float* src;
        switch (tns) {
            case 0: src = eWq; break; case 1: src = eWk; break; case 2: src = eWv; break;
            case 3: src = eWo; break; case 4: src = eW1; break; case 5: src = mWq; break;
            case 6: src = mWk; break; case 7: src = mWv; break; case 8: src = mWo; break;
            default: src = mW2; break;
        }
        const float4* p = (const float4*)(src + off);
        float4 a = p[0], b = p[1];
        uint4 o;
        o.x = pack2(f2bf(a.x), f2bf(a.y));
        o.y = pack2(f2bf(a.z), f2bf(a.w));
        o.z = pack2(f2bf(b.x), f2bf(b.y));
        o.w = pack2(f2bf(b.z), f2bf(b.w));
        *(uint4*)(Wb + tns * 65536 + off) = o;
    } else {
        int i = (bid - 1344) * 256 + tid;     // 4096 = 1024 n * 4 e
        int n = i >> 2, e = i & 3;
        const float4* a = (const float4*)(mm + (size_t)n * DD);
        const float4* w = (const float4*)(Wr + (size_t)e * DD);
        float s = 0.f;
#pragma unroll
        for (int j = 0; j < 32; j++) {
            float4 av = a[j], wv = w[j];
            s += av.x * wv.x + av.y * wv.y + av.z * wv.z + av.w * wv.w;
        }
        logits[i] = s + br[e];
    }
}

// ---------------- routing: softmax, top2, capacity (ballot scan), masks, loss, zero stats ---
__global__ __launch_bounds__(1024) void k_route(const float* __restrict__ logits, const int* __restrict__ modix,
                                                float* __restrict__ mask8, float* __restrict__ comb8,
                                                float* __restrict__ cnt8, float* __restrict__ bnsum,
                                                float* __restrict__ bnsq, float* __restrict__ loss) {
    __shared__ int wsum[4][16];
    __shared__ float red[16];
    int n = threadIdx.x;
    if (n < 16) red[n] = 0.f;
    bnsum[n] = 0.f; bnsq[n] = 0.f;                      // zero [8][128] stats
    float g[4];
    float mx = -1e30f;
#pragma unroll
    for (int e = 0; e < 4; e++) { g[e] = logits[n * 4 + e]; mx = fmaxf(mx, g[e]); }
    float s = 0.f;
#pragma unroll
    for (int e = 0; e < 4; e++) { g[e] = expf(g[e] - mx); s += g[e]; }
    float inv = 1.f / s;
#pragma unroll
    for (int e = 0; e < 4; e++) g[e] *= inv;
    // top2 of gate (ties -> lower index, matching lax.top_k)
    int i0 = 0; float b0 = g[0];
#pragma unroll
    for (int e = 1; e < 4; e++) if (g[e] > b0) { b0 = g[e]; i0 = e; }
    int i1 = -1; float b1v = -1e30f;
#pragma unroll
    for (int e = 0; e < 4; e++) if (e != i0 && g[e] > b1v) { b1v = g[e]; i1 = e; }
    u32 rbits = (1u << i0) | (1u << i1);
    // inclusive cumsum per expert via wave ballot + cross-wave scan; keep iff <= N/E = 256
    int wav = n >> 6, lane = n & 63;
    unsigned long long lm = (~0ull) >> (63 - lane);     // bits 0..lane
    int pre[4];
#pragma unroll
    for (int e = 0; e < 4; e++) {
        unsigned long long m = __ballot((rbits >> e) & 1u);
        pre[e] = __popcll(m & lm);
        if (lane == 63) wsum[e][wav] = __popcll(m);
    }
    __syncthreads();
    float rp[4]; float rsum = 0.f;
#pragma unroll
    for (int e = 0; e < 4; e++) {
        int off = 0;
        for (int w = 0; w < 16; w++) if (w < wav) off += wsum[e][w];
        bool keep = (off + pre[e]) <= 256;
        rp[e] = (((rbits >> e) & 1u) && keep) ? g[e] : 0.f;
        rsum += rp[e];
    }
    bool active = rsum > 0.f;
    // top2 of rprobs (reproduce lax.top_k filler-index tie-break for the BN mask)
    int j0 = 0; float c0 = rp[0];
#pragma unroll
    for (int e = 1; e < 4; e++) if (rp[e] > c0) { c0 = rp[e]; j0 = e; }
    int j1 = -1; float c1 = -1e30f;
#pragma unroll
    for (int e = 0; e < 4; e++) if (e != j0 && rp[e] > c1) { c1 = rp[e]; j1 = e; }
    float vals[16];
#pragma unroll
    for (int e = 0; e < 4; e++) {
        bool sel = active && (e == j0 || e == j1);
        float mf = sel ? 1.f : 0.f;
        mask8[e * NTOK + n] = mf;
        comb8[e * NTOK + n] = rp[e];
        vals[e] = mf;
    }
#pragma unroll
    for (int m = 0; m < 4; m++) {
        float mf = (modix[n * 4 + m] == 1) ? 1.f : 0.f;
        mask8[(4 + m) * NTOK + n] = mf;
        comb8[(4 + m) * NTOK + n] = 0.25f * mf;         // mod_out / Mn folded in
        vals[4 + m] = mf;
    }
#pragma unroll
    for (int e = 0; e < 4; e++) vals[8 + e] = ((rbits >> e) & 1u) ? 1.f : 0.f;
#pragma unroll
    for (int e = 0; e < 4; e++) vals[12 + e] = g[e];
#pragma unroll
    for (int q = 0; q < 16; q++) {
        float v = vals[q];
        for (int off = 32; off; off >>= 1) v += __shfl_down(v, off, 64);
        if (lane == 0) atomicAdd(&red[q], v);
    }
    __syncthreads();
    if (n == 0) {
        for (int c = 0; c < 8; c++) cnt8[c] = fmaxf(16.f * red[c], 1.f);
        float l = 0.f;
        for (int e = 0; e < 4; e++) l += (red[8 + e] / 1024.f) * (red[12 + e] / 1024.f);
        loss[0] = 4.f * l;
    }
}

// ---------------- batched QKV projection: grid (256 bm, 8 c), bf16 weights, Q mask-skip ----
__global__ __launch_bounds__(256) void k_gemm_qkv(const u16* __restrict__ Xb, const u16* __restrict__ Wb,
        const float* __restrict__ ebq, const float* __restrict__ mbq,
        const float* __restrict__ mask8,
        u16* __restrict__ Qb, u16* __restrict__ Kb, u16* __restrict__ Vb) {
    __shared__ u16 As[64 * 128];
    __shared__ u16 Bs[128 * 128];
    int tid = threadIdx.x; int bm = blockIdx.x; int c = blockIdx.y;
    int wq = (c < 4) ? c : 20 + (c - 4);
    int wk = (c < 4) ? 4 + c : 24 + (c - 4);
    int wv = (c < 4) ? 8 + c : 28 + (c - 4);
    const u16* Wsl[3] = { Wb + wq * 16384, Wb + wk * 16384, Wb + wv * 16384 };
    const float* bq = (c < 4) ? (ebq + c * 128) : (mbq + (c - 4) * 128);
    u16* Os[3] = { Qb + (size_t)c * ST, Kb + (size_t)c * ST, Vb + (size_t)c * ST };
    const float* maskp = mask8 + c * NTOK;
    bool qact = (maskp[bm * 4] != 0.f) || (maskp[bm * 4 + 1] != 0.f) ||
                (maskp[bm * 4 + 2] != 0.f) || (maskp[bm * 4 + 3] != 0.f);

    const uint4* asrc = (const uint4*)(Xb + (size_t)bm * 8192);
#pragma unroll
    for (int it = 0; it < 4; ++it) {
        int ci = it * 256 + tid;
        uint4 v = asrc[ci];
        int byte = ci * 16; int row = byte >> 8;
        *(uint4*)((char*)As + (byte ^ ((row & 7) << 4))) = v;
    }
    __syncthreads();
    int lane = tid & 63, wid = tid >> 6, lr = lane & 15, lg = lane >> 4;
    short8 a[4];
#pragma unroll
    for (int ks = 0; ks < 4; ++ks) {
        int kk = ks * 64 + lg * 16;
        int arow = wid * 16 + lr;
        a[ks] = *(const short8*)((const char*)As + ((arow * 256 + kk) ^ ((arow & 7) << 4)));
    }
    for (int y = 0; y < 3; ++y) {
        if (y == 0 && !qact) continue;   // Q only read for masked tokens (block-uniform skip)
        const uint4* wsrc = (const uint4*)Wsl[y];
#pragma unroll
        for (int it = 0; it < 8; ++it) {
            int qi = it * 256 + tid;
            uint4 v = wsrc[qi];
            int eo = qi * 8; int row = eo >> 7; int byte = eo * 2;
            *(uint4*)((char*)Bs + (byte ^ ((row & 7) << 4))) = v;
        }
        __syncthreads();
        f32x4 acc[8] = {};
#pragma unroll
        for (int ks = 0; ks < 4; ++ks) {
            int kk = ks * 64 + lg * 16;
#pragma unroll
            for (int nc = 0; nc < 8; ++nc) {
                int brow = nc * 16 + lr;
                short8 b = *(const short8*)((const char*)Bs + ((brow * 256 + kk) ^ ((brow & 7) << 4)));
                acc[nc] = __builtin_amdgcn_mfma_f32_16x16x32_bf16(a[ks], b, acc[nc], 0, 0, 0);
            }
        }
        int row0 = bm * 64 + wid * 16 + lg * 4;
        u16* Op = Os[y];
        bool hasb = (y == 0);
#pragma unroll
        for (int nc = 0; nc < 8; ++nc) {
            int col = nc * 16 + lr;
            float bb = hasb ? bq[col] : 0.f;
#pragma unroll
            for (int r = 0; r < 4; r++)
                Op[(size_t)(row0 + r) * 128 + col] = f2bf(acc[nc][r] + bb);
        }
        __syncthreads();
    }
}

// ---------------- gather attention, split-k: 2 threads per (t,h), 8 neighbors each --------
// grid 8192 linear, c = bid&7 (XCD pin); wave-uniform n mask skip. Ob aliases Qb slice.
__global__ __launch_bounds__(256) void k_attn(const u16* Qb, const u16* __restrict__ Kb,
        const u16* __restrict__ Vb, const float* __restrict__ tkv, const int* __restrict__ idx,
        const float* __restrict__ ebk, const float* __restrict__ ebv,
        const float* __restrict__ mbk, const float* __restrict__ mbv,
        const float* __restrict__ mask8, u16* Ob) {
    int bid = blockIdx.x;
    int c = bid & 7, inner = bid >> 3;     // expert -> XCD pinning (round-robin dispatch)
    int tid = threadIdx.x;
    int gid = inner * 256 + tid;           // 262144 = 16384 t * 8 h * 2 half
    int half = gid & 1;
    int h = (gid >> 1) & 7;
    int t = gid >> 4;
    int n = __builtin_amdgcn_readfirstlane(t >> 4);   // wave spans 4 consecutive t, same n
    int bl = t & 15;
    if (mask8[c * NTOK + n] == 0.f) return;           // wave-uniform skip
    const u16* Qc = Qb + (size_t)c * ST;
    const u16* Kc = Kb + (size_t)c * ST;
    const u16* Vc = Vb + (size_t)c * ST;
    u16* Oc = Ob + (size_t)c * ST;
    const float* bk = (c < 4) ? (ebk + c * 128) : (mbk + (c - 4) * 128);
    const float* bv = (c < 4) ? (ebv + c * 128) : (mbv + (c - 4) * 128);
    float qv[16];
    {
        const uint4* qp = (const uint4*)(Qc + (size_t)t * 128 + h * 16);
        uint4 a = qp[0], b = qp[1];
        up2(a.x, qv[0], qv[1]);   up2(a.y, qv[2], qv[3]);
        up2(a.z, qv[4], qv[5]);   up2(a.w, qv[6], qv[7]);
        up2(b.x, qv[8], qv[9]);   up2(b.y, qv[10], qv[11]);
        up2(b.z, qv[12], qv[13]); up2(b.w, qv[14], qv[15]);
    }
    float qb = 0.f;
#pragma unroll
    for (int i = 0; i < 16; i++) qb += qv[i] * bk[h * 16 + i];
    // this thread's 8 neighbors (kb is per-lane divergent -> plain loads, NO readfirstlane)
    int kb = half * 8;
    int gsav[8]; float tsav[8];
#pragma unroll
    for (int k = 0; k < 8; k++) {
        gsav[k] = idx[n * 16 + kb + k];
        tsav[k] = tkv[n * 16 + kb + k];
    }
    float scv[8]; float smax = -1e30f;
#pragma unroll
    for (int k = 0; k < 8; k++) {
        const uint4* kp = (const uint4*)(Kc + (size_t)(gsav[k] * 16 + bl) * 128 + h * 16);
        uint4 a = kp[0], b = kp[1];
        float d0 = 0.f, d1 = 0.f, lo, hi;
        up2(a.x, lo, hi); d0 = fmaf(lo, qv[0], d0);  d1 = fmaf(hi, qv[1], d1);
        up2(a.y, lo, hi); d0 = fmaf(lo, qv[2], d0);  d1 = fmaf(hi, qv[3], d1);
        up2(a.z, lo, hi); d0 = fmaf(lo, qv[4], d0);  d1 = fmaf(hi, qv[5], d1);
        up2(a.w, lo, hi); d0 = fmaf(lo, qv[6], d0);  d1 = fmaf(hi, qv[7], d1);
        up2(b.x, lo, hi); d0 = fmaf(lo, qv[8], d0);  d1 = fmaf(hi, qv[9], d1);
        up2(b.y, lo, hi); d0 = fmaf(lo, qv[10], d0); d1 = fmaf(hi, qv[11], d1);
        up2(b.z, lo, hi); d0 = fmaf(lo, qv[12], d0); d1 = fmaf(hi, qv[13], d1);
        up2(b.w, lo, hi); d0 = fmaf(lo, qv[14], d0); d1 = fmaf(hi, qv[15], d1);
        float sv = 0.25f * (tsav[k] * (d0 + d1) + qb);   // k = tkv*kx + bk ; 1/sqrt(dh)=0.25
        scv[k] = sv; smax = fmaxf(smax, sv);
    }
    smax = fmaxf(smax, __shfl_xor(smax, 1, 64));         // pair-combined row max
    float sum = 0.f;
#pragma unroll
    for (int k = 0; k < 8; k++) { scv[k] = __expf(scv[k] - smax); sum += scv[k]; }
    sum += __shfl_xor(sum, 1, 64);                       // pair-combined denom
    float inv = 1.f / sum;
    float o[16];
#pragma unroll
    for (int i = 0; i < 16; i++) o[i] = 0.f;
#pragma unroll
    for (int k = 0; k < 8; k++) {
        const uint4* vp = (const uint4*)(Vc + (size_t)(gsav[k] * 16 + bl) * 128 + h * 16);
        uint4 a = vp[0], b = vp[1];
        float cc = scv[k] * inv * tsav[k];
        float lo, hi;
        up2(a.x, lo, hi); o[0] = fmaf(lo, cc, o[0]);   o[1] = fmaf(hi, cc, o[1]);
        up2(a.y, lo, hi); o[2] = fmaf(lo, cc, o[2]);   o[3] = fmaf(hi, cc, o[3]);
        up2(a.z, lo, hi); o[4] = fmaf(lo, cc, o[4]);   o[5] = fmaf(hi, cc, o[5]);
        up2(a.w, lo, hi); o[6] = fmaf(lo, cc, o[6]);   o[7] = fmaf(hi, cc, o[7]);
        up2(b.x, lo, hi); o[8] = fmaf(lo, cc, o[8]);   o[9] = fmaf(hi, cc, o[9]);
        up2(b.y, lo, hi); o[10] = fmaf(lo, cc, o[10]); o[11] = fmaf(hi, cc, o[11]);
        up2(b.z, lo, hi); o[12] = fmaf(lo, cc, o[12]); o[13] = fmaf(hi, cc, o[13]);
        up2(b.w, lo, hi); o[14] = fmaf(lo, cc, o[14]); o[15] = fmaf(hi, cc, o[15]);
    }
    // pair-combine the 16-dim partial outputs
#pragma unroll
    for (int i = 0; i < 16; i++) o[i] += __shfl_xor(o[i], 1, 64);
    // each half writes its 8 elements (+bv; sum(attn)=1)
    int e0 = half * 8;
    uint4 s;
    s.x = pack2(f2bf(o[e0 + 0] + bv[h * 16 + e0 + 0]), f2bf(o[e0 + 1] + bv[h * 16 + e0 + 1]));
    s.y = pack2(f2bf(o[e0 + 2] + bv[h * 16 + e0 + 2]), f2bf(o[e0 + 3] + bv[h * 16 + e0 + 3]));
    s.z = pack2(f2bf(o[e0 + 4] + bv[h * 16 + e0 + 4]), f2bf(o[e0 + 5] + bv[h * 16 + e0 + 5]));
    s.w = pack2(f2bf(o[e0 + 6] + bv[h * 16 + e0 + 6]), f2bf(o[e0 + 7] + bv[h * 16 + e0 + 7]));
    *(uint4*)(Oc + (size_t)t * 128 + h * 16 + e0) = s;
}

// ---------------- O @ Wo.T + bo with masked BN stats; block skip; bf16 O2: grid (256,8) ----
__global__ __launch_bounds__(256) void k_gemm_o(const u16* __restrict__ Ab, const u16* __restrict__ Wb,
        const float* __restrict__ ebo, const float* __restrict__ mbo,
        u16* __restrict__ O2, const float* __restrict__ mask8,
        float* __restrict__ bnsum, float* __restrict__ bnsq) {
    __shared__ u16 As[64 * 128];
    __shared__ u16 Bs[128 * 128];
    __shared__ float ssum[128], ssq[128];
    int tid = threadIdx.x; int bm = blockIdx.x; int c = blockIdx.y;
    const float* maskp = mask8 + c * NTOK;
    // whole-block skip: all 4 tokens masked out => O2 never consumed, no stats
    if (maskp[bm * 4] == 0.f && maskp[bm * 4 + 1] == 0.f &&
        maskp[bm * 4 + 2] == 0.f && maskp[bm * 4 + 3] == 0.f) return;
    int wo = (c < 4) ? 12 + c : 32 + (c - 4);
    const u16* Wp = Wb + wo * 16384;
    const float* bo = (c < 4) ? (ebo + c * 128) : (mbo + (c - 4) * 128);
    if (tid < 128) { ssum[tid] = 0.f; ssq[tid] = 0.f; }
    const uint4* asrc = (const uint4*)(Ab + (size_t)c * ST + (size_t)bm * 8192);
#pragma unroll
    for (int it = 0; it < 4; ++it) {
        int ci = it * 256 + tid;
        uint4 v = asrc[ci];
        int byte = ci * 16; int row = byte >> 8;
        *(uint4*)((char*)As + (byte ^ ((row & 7) << 4))) = v;
    }
    const uint4* wsrc = (const uint4*)Wp;
#pragma unroll
    for (int it = 0; it < 8; ++it) {
        int qi = it * 256 + tid;
        uint4 v = wsrc[qi];
        int eo = qi * 8; int row = eo >> 7; int byte = eo * 2;
        *(uint4*)((char*)Bs + (byte ^ ((row & 7) << 4))) = v;
    }
    __syncthreads();
    int lane = tid & 63, wid = tid >> 6, lr = lane & 15, lg = lane >> 4;
    f32x4 acc[8] = {};
#pragma unroll
    for (int ks = 0; ks < 4; ++ks) {
        int kk = ks * 64 + lg * 16;
        int arow = wid * 16 + lr;
        short8 a = *(const short8*)((const char*)As + ((arow * 256 + kk) ^ ((arow & 7) << 4)));
#pragma unroll
        for (int nc = 0; nc < 8; ++nc) {
            int brow = nc * 16 + lr;
            short8 b = *(const short8*)((const char*)Bs + ((brow * 256 + kk) ^ ((brow & 7) << 4)));
            acc[nc] = __builtin_amdgcn_mfma_f32_16x16x32_bf16(a, b, acc[nc], 0, 0, 0);
        }
    }
    int nidx = bm * 4 + wid;
    float mk = maskp[nidx];
    int row0 = bm * 64 + wid * 16 + lg * 4;
    u16* O2c = O2 + (size_t)c * ST;
    float ps[8], pq[8];
#pragma unroll
    for (int nc = 0; nc < 8; ++nc) {
        int col = nc * 16 + lr;
        float bb = bo[col];
        float sv = 0.f, qv = 0.f;
#pragma unroll
        for (int r = 0; r < 4; r++) {
            float v = acc[nc][r] + bb;
            if (mk != 0.f) O2c[(size_t)(row0 + r) * 128 + col] = f2bf(v);
            sv += v; qv += v * v;
        }
        ps[nc] = sv * mk; pq[nc] = qv * mk;
    }
#pragma unroll
    for (int nc = 0; nc < 8; ++nc) {
        ps[nc] += __shfl_xor(ps[nc], 16, 64); ps[nc] += __shfl_xor(ps[nc], 32, 64);
        pq[nc] += __shfl_xor(pq[nc], 16, 64); pq[nc] += __shfl_xor(pq[nc], 32, 64);
    }
    if (lane < 16) {
#pragma unroll
        for (int nc = 0; nc < 8; ++nc) {
            atomicAdd(&ssum[nc * 16 + lane], ps[nc]);
            atomicAdd(&ssq[nc * 16 + lane], pq[nc]);
        }
    }
    __syncthreads();
    if (tid < 128) { atomicAdd(&bnsum[c * 128 + tid], ssum[tid]); atomicAdd(&bnsq[c * 128 + tid], ssq[tid]); }
}

// ---------------- fused final GEMM over 8 experts, 512 threads (8 waves): grid 256 ----------
__global__ __launch_bounds__(512) void k_gemm_w1(const u16* __restrict__ O2, const u16* __restrict__ Xb,
        const u16* __restrict__ Wb, const float* __restrict__ eb1, const float* __restrict__ mb2,
        const float* __restrict__ eGamma, const float* __restrict__ mGamma,
        const float* __restrict__ eBeta, const float* __restrict__ mBeta,
        const float* __restrict__ comb8, const float* __restrict__ cnt8,
        const float* __restrict__ bnsum, const float* __restrict__ bnsq,
        float* __restrict__ out) {
    __shared__ u16 As[64 * 128];
    __shared__ u16 Bs[128 * 128];
    __shared__ float scall[8][128], shall[8][128];
    int tid = threadIdx.x; int bm = blockIdx.x;
    // BN scale/shift for all 8 experts
#pragma unroll
    for (int j = 0; j < 2; ++j) {
        int id = j * 512 + tid;
        int c = id >> 7, d = id & 127;
        float cnt = cnt8[c];
        float mean = bnsum[c * 128 + d] / cnt;
        float var = bnsq[c * 128 + d] / cnt - mean * mean;
        float rs = rsqrtf(var + EPSV);
        const float* ga = (c < 4) ? (eGamma + c * 128) : (mGamma + (c - 4) * 128);
        const float* be = (c < 4) ? (eBeta + c * 128) : (mBeta + (c - 4) * 128);
        float gg = ga[d];
        scall[c][d] = rs * gg;
        shall[c][d] = be[d] - mean * rs * gg;
    }
    __syncthreads();
    int lane = tid & 63, wid = tid >> 6, lr = lane & 15, lg = lane >> 4;
    int wm = wid & 3, wn = wid >> 2;        // 4 m-frags x 2 n-halves
    f32x4 acc[4] = {};
    const uint4* xsrc = (const uint4*)(Xb + (size_t)bm * 8192);
    for (int c = 0; c < 8; ++c) {
        float wc4[4];
        wc4[0] = comb8[c * NTOK + bm * 4];     wc4[1] = comb8[c * NTOK + bm * 4 + 1];
        wc4[2] = comb8[c * NTOK + bm * 4 + 2]; wc4[3] = comb8[c * NTOK + bm * 4 + 3];
        if (wc4[0] == 0.f && wc4[1] == 0.f && wc4[2] == 0.f && wc4[3] == 0.f) continue;
        int wsl = (c < 4) ? 16 + c : 36 + (c - 4);
        const u16* Wp = Wb + wsl * 16384;
        const uint4* osrc = (const uint4*)(O2 + (size_t)c * ST + (size_t)bm * 8192);
        // stage A = wc * (BN(O2) + x), bf16
#pragma unroll
        for (int it = 0; it < 2; ++it) {
            int qi = it * 512 + tid;
            int eo = qi * 8; int row = eo >> 7; int cb = eo & 127;
            float wc = wc4[row >> 4];
            uint4 ov = osrc[qi]; uint4 xv = xsrc[qi];
            float olo, ohi, xlo, xhi;
            uint4 hh;
            up2(ov.x, olo, ohi); up2(xv.x, xlo, xhi);
            hh.x = pack2(f2bf((olo * scall[c][cb] + shall[c][cb] + xlo) * wc),
                         f2bf((ohi * scall[c][cb + 1] + shall[c][cb + 1] + xhi) * wc));
            up2(ov.y, olo, ohi); up2(xv.y, xlo, xhi);
            hh.y = pack2(f2bf((olo * scall[c][cb + 2] + shall[c][cb + 2] + xlo) * wc),
                         f2bf((ohi * scall[c][cb + 3] + shall[c][cb + 3] + xhi) * wc));
            up2(ov.z, olo, ohi); up2(xv.z, xlo, xhi);
            hh.z = pack2(f2bf((olo * scall[c][cb + 4] + shall[c][cb + 4] + xlo) * wc),
                         f2bf((ohi * scall[c][cb + 5] + shall[c][cb + 5] + xhi) * wc));
            up2(ov.w, olo, ohi); up2(xv.w, xlo, xhi);
            hh.w = pack2(f2bf((olo * scall[c][cb + 6] + shall[c][cb + 6] + xlo) * wc),
                         f2bf((ohi * scall[c][cb + 7] + shall[c][cb + 7] + xhi) * wc));
            *(uint4*)((char*)As + ((eo * 2) ^ ((row & 7) << 4))) = hh;
        }
        const uint4* wsrc = (const uint4*)Wp;
#pragma unroll
        for (int it = 0; it < 4; ++it) {
            int qi = it * 512 + tid;
            uint4 v = wsrc[qi];
            int eo = qi * 8; int row = eo >> 7; int byte = eo * 2;
            *(uint4*)((char*)Bs + (byte ^ ((row & 7) << 4))) = v;
        }
        __syncthreads();
#pragma unroll
        for (int ks = 0; ks < 4; ++ks) {
            int kk = ks * 64 + lg * 16;
            int arow = wm * 16 + lr;
            short8 a = *(const short8*)((const char*)As + ((arow * 256 + kk) ^ ((arow & 7) << 4)));
#pragma unroll
            for (int nc = 0; nc < 4; ++nc) {
                int brow = wn * 64 + nc * 16 + lr;
                short8 b = *(const short8*)((const char*)Bs + ((brow * 256 + kk) ^ ((brow & 7) << 4)));
                acc[nc] = __builtin_amdgcn_mfma_f32_16x16x32_bf16(a, b, acc[nc], 0, 0, 0);
            }
        }
        __syncthreads();
    }
    // epilogue: add Sum_c wc*b1_c and write out once
    int nidx = bm * 4 + wm;
    int row0 = bm * 64 + wm * 16 + lg * 4;
    float wc8[8];
#pragma unroll
    for (int c = 0; c < 8; ++c) wc8[c] = comb8[c * NTOK + nidx];
#pragma unroll
    for (int nc = 0; nc < 4; ++nc) {
        int col = wn * 64 + nc * 16 + lr;
        float bias = 0.f;
#pragma unroll
        for (int c = 0; c < 8; ++c) {
            const float* b1 = (c < 4) ? (eb1 + c * 128) : (mb2 + (c - 4) * 128);
            bias += wc8[c] * b1[col];
        }
#pragma unroll
        for (int r = 0; r < 4; r++)
            out[(size_t)(row0 + r) * 128 + col] = acc[nc][r] + bias;
    }
}

extern "C" void kernel_launch(void* const* d_in, const int* in_sizes, int n_in,
                              void* d_out, int out_size, void* d_ws, size_t ws_size,
                              hipStream_t stream) {
    (void)in_sizes; (void)n_in; (void)ws_size; (void)out_size;
    const float* x    = (const float*)d_in[0];
    const float* mm   = (const float*)d_in[1];
    const float* tkv  = (const float*)d_in[2];
    const int*   idx  = (const int*)d_in[3];
    const int*   modi = (const int*)d_in[4];
    const float* Wr   = (const float*)d_in[5];
    const float* br   = (const float*)d_in[6];
    const float* eWq = (const float*)d_in[7],  *eWk = (const float*)d_in[8],  *eWv = (const float*)d_in[9];
    const float* eWo = (const float*)d_in[10], *eW1 = (const float*)d_in[11];
    const float* mWq = (const float*)d_in[12], *mWk = (const float*)d_in[13], *mWv = (const float*)d_in[14];
    const float* mWo = (const float*)d_in[15], *mW2 = (const float*)d_in[16];
    const float* ebq = (const float*)d_in[17], *ebk = (const float*)d_in[18], *ebv = (const float*)d_in[19];
    const float* ebo = (const float*)d_in[20], *eBeta = (const float*)d_in[21], *eb1 = (const float*)d_in[22];
    const float* mbq = (const float*)d_in[23], *mbk = (const float*)d_in[24], *mbv = (const float*)d_in[25];
    const float* mbo = (const float*)d_in[26], *mBeta = (const float*)d_in[27], *mb2 = (const float*)d_in[28];
    const float* eGamma = (const float*)d_in[29], *mGamma = (const float*)d_in[30];
    float* out = (float*)d_out;

    char* wsb = (char*)d_ws;
    const size_t MB = 1024 * 1024;
    u16* Xb = (u16*)wsb;                        // 0..4 MB
    u16* Wb = (u16*)(wsb + 4 * MB);             // 4..5.3 MB (40 x 16384 bf16)
    u16* Qb = (u16*)(wsb + 8 * MB);             // 8..40 MB  (attn O in-place)
    u16* Kb = (u16*)(wsb + 40 * MB);            // 40..72 MB
    u16* Vb = (u16*)(wsb + 72 * MB);            // 72..104 MB
    u16* O2 = (u16*)(wsb + 104 * MB);           // 104..136 MB (bf16)
    float* logits = (float*)(wsb + 136 * MB);
    float* comb8 = logits + 4096;               // [8][1024]
    float* mask8 = comb8 + 8192;                // [8][1024]
    float* cnt8  = mask8 + 8192;                // [8]
    float* bnsum = cnt8 + 16;                   // [8][128]
    float* bnsq  = bnsum + 1024;                // [8][128]

    k_prep<<<1360, 256, 0, stream>>>(x, eWq, eWk, eWv, eWo, eW1, mWq, mWk, mWv, mWo, mW2,
                                     mm, Wr, br, Xb, Wb, logits);
    k_route<<<1, 1024, 0, stream>>>(logits, modi, mask8, comb8, cnt8, bnsum, bnsq,
                                    out + (size_t)TT * DD);
    k_gemm_qkv<<<dim3(256, 8), 256, 0, stream>>>(Xb, Wb, ebq, mbq, mask8, Qb, Kb, Vb);
    k_attn<<<8192, 256, 0, stream>>>(Qb, Kb, Vb, tkv, idx, ebk, ebv, mbk, mbv, mask8, Qb);
    k_gemm_o<<<dim3(256, 8), 256, 0, stream>>>(Qb, Wb, ebo, mbo, O2, mask8, bnsum, bnsq);
    k_gemm_w1<<<256, 512, 0, stream>>>(O2, Xb, Wb, eb1, mb2, eGamma, mGamma, eBeta, mBeta,
                                       comb8, cnt8, bnsum, bnsq, out);
}

// Round 9
// 117.819 us; speedup vs baseline: 1.1286x; 1.0611x over previous
//
#include <hip/hip_runtime.h>

typedef unsigned short u16;
typedef unsigned int u32;
typedef short short8 __attribute__((ext_vector_type(8)));
typedef float f32x4 __attribute__((ext_vector_type(4)));

#define NTOK 1024
#define TT 16384   // N*B*L tokens
#define DD 128
#define EPSV 1e-5f
#define ST 2097152 // TT*DD, elements per expert-slice (Q/O, O2)
#define STKV 4194304 // TT*256, elements per expert KV slice (K|V interleaved)

__device__ __forceinline__ u16 f2bf(float f) {
    u32 u = __float_as_uint(f);
    u += 0x7fffu + ((u >> 16) & 1u);
    return (u16)(u >> 16);
}
__device__ __forceinline__ u32 pack2(u16 a, u16 b) { return (u32)a | ((u32)b << 16); }
// cheap bf16-pair unpack: 1 VALU per element
__device__ __forceinline__ void up2(u32 w, float& lo, float& hi) {
    lo = __uint_as_float(w << 16);
    hi = __uint_as_float(w & 0xffff0000u);
}

// ---------------- fused prep: x->bf16 | weights->bf16 | router logits ----------------
// blocks [0,1024): cvt x ; [1024,1344): cvt weights ; [1344,1360): logits
__global__ __launch_bounds__(256) void k_prep(const float* __restrict__ x,
        const float* __restrict__ eWq, const float* __restrict__ eWk,
        const float* __restrict__ eWv, const float* __restrict__ eWo, const float* __restrict__ eW1,
        const float* __restrict__ mWq, const float* __restrict__ mWk, const float* __restrict__ mWv,
        const float* __restrict__ mWo, const float* __restrict__ mW2,
        const float* __restrict__ mm, const float* __restrict__ Wr, const float* __restrict__ br,
        u16* __restrict__ Xb, u16* __restrict__ Wb, float* __restrict__ logits) {
    int bid = blockIdx.x; int tid = threadIdx.x;
    if (bid < 1024) {
        int i = bid * 256 + tid;
        const float4* p = (const float4*)x + (size_t)i * 2;
        float4 a = p[0], b = p[1];
        uint4 o;
        o.x = pack2(f2bf(a.x), f2bf(a.y));
        o.y = pack2(f2bf(a.z), f2bf(a.w));
        o.z = pack2(f2bf(b.x), f2bf(b.y));
        o.w = pack2(f2bf(b.z), f2bf(b.w));
        *((uint4*)Xb + i) = o;
    } else if (bid < 1344) {
        int i = (bid - 1024) * 256 + tid;     // 81920 threads, 8 elems each
        int tns = i >> 13;
        int off = (i & 8191) * 8;
        const float* src;
        switch (tns) {
            case 0: src = eWq; break; case 1: src = eWk; break; case 2: src = eWv; break;
            case 3: src = eWo; break; case 4: src = eW1; break; case 5: src = mWq; break;
            case 6: src = mWk; break; case 7: src = mWv; break; case 8: src = mWo; break;
            default: src = mW2; break;
        }
        const float4* p = (const float4*)(src + off);
        float4 a = p[0], b = p[1];
        uint4 o;
        o.x = pack2(f2bf(a.x), f2bf(a.y));
        o.y = pack2(f2bf(a.z), f2bf(a.w));
        o.z = pack2(f2bf(b.x), f2bf(b.y));
        o.w = pack2(f2bf(b.z), f2bf(b.w));
        *(uint4*)(Wb + tns * 65536 + off) = o;
    } else {
        int i = (bid - 1344) * 256 + tid;     // 4096 = 1024 n * 4 e
        int n = i >> 2, e = i & 3;
        const float4* a = (const float4*)(mm + (size_t)n * DD);
        const float4* w = (const float4*)(Wr + (size_t)e * DD);
        float s = 0.f;
#pragma unroll
        for (int j = 0; j < 32; j++) {
            float4 av = a[j], wv = w[j];
            s += av.x * wv.x + av.y * wv.y + av.z * wv.z + av.w * wv.w;
        }
        logits[i] = s + br[e];
    }
}

// ---------------- routing: softmax, top2, capacity (ballot scan), masks, loss, zero stats ---
__global__ __launch_bounds__(1024) void k_route(const float* __restrict__ logits, const int* __restrict__ modix,
                                                float* __restrict__ mask8, float* __restrict__ comb8,
                                                float* __restrict__ cnt8, float* __restrict__ bnsum,
                                                float* __restrict__ bnsq, float* __restrict__ loss) {
    __shared__ int wsum[4][16];
    __shared__ float red[16];
    int n = threadIdx.x;
    if (n < 16) red[n] = 0.f;
    bnsum[n] = 0.f; bnsq[n] = 0.f;                      // zero [8][128] stats
    float g[4];
    float mx = -1e30f;
#pragma unroll
    for (int e = 0; e < 4; e++) { g[e] = logits[n * 4 + e]; mx = fmaxf(mx, g[e]); }
    float s = 0.f;
#pragma unroll
    for (int e = 0; e < 4; e++) { g[e] = expf(g[e] - mx); s += g[e]; }
    float inv = 1.f / s;
#pragma unroll
    for (int e = 0; e < 4; e++) g[e] *= inv;
    // top2 of gate (ties -> lower index, matching lax.top_k)
    int i0 = 0; float b0 = g[0];
#pragma unroll
    for (int e = 1; e < 4; e++) if (g[e] > b0) { b0 = g[e]; i0 = e; }
    int i1 = -1; float b1v = -1e30f;
#pragma unroll
    for (int e = 0; e < 4; e++) if (e != i0 && g[e] > b1v) { b1v = g[e]; i1 = e; }
    u32 rbits = (1u << i0) | (1u << i1);
    // inclusive cumsum per expert via wave ballot + cross-wave scan; keep iff <= N/E = 256
    int wav = n >> 6, lane = n & 63;
    unsigned long long lm = (~0ull) >> (63 - lane);     // bits 0..lane
    int pre[4];
#pragma unroll
    for (int e = 0; e < 4; e++) {
        unsigned long long m = __ballot((rbits >> e) & 1u);
        pre[e] = __popcll(m & lm);
        if (lane == 63) wsum[e][wav] = __popcll(m);
    }
    __syncthreads();
    float rp[4]; float rsum = 0.f;
#pragma unroll
    for (int e = 0; e < 4; e++) {
        int off = 0;
        for (int w = 0; w < 16; w++) if (w < wav) off += wsum[e][w];
        bool keep = (off + pre[e]) <= 256;
        rp[e] = (((rbits >> e) & 1u) && keep) ? g[e] : 0.f;
        rsum += rp[e];
    }
    bool active = rsum > 0.f;
    // top2 of rprobs (reproduce lax.top_k filler-index tie-break for the BN mask)
    int j0 = 0; float c0 = rp[0];
#pragma unroll
    for (int e = 1; e < 4; e++) if (rp[e] > c0) { c0 = rp[e]; j0 = e; }
    int j1 = -1; float c1 = -1e30f;
#pragma unroll
    for (int e = 0; e < 4; e++) if (e != j0 && rp[e] > c1) { c1 = rp[e]; j1 = e; }
    float vals[16];
#pragma unroll
    for (int e = 0; e < 4; e++) {
        bool sel = active && (e == j0 || e == j1);
        float mf = sel ? 1.f : 0.f;
        mask8[e * NTOK + n] = mf;
        comb8[e * NTOK + n] = rp[e];
        vals[e] = mf;
    }
#pragma unroll
    for (int m = 0; m < 4; m++) {
        float mf = (modix[n * 4 + m] == 1) ? 1.f : 0.f;
        mask8[(4 + m) * NTOK + n] = mf;
        comb8[(4 + m) * NTOK + n] = 0.25f * mf;         // mod_out / Mn folded in
        vals[4 + m] = mf;
    }
#pragma unroll
    for (int e = 0; e < 4; e++) vals[8 + e] = ((rbits >> e) & 1u) ? 1.f : 0.f;
#pragma unroll
    for (int e = 0; e < 4; e++) vals[12 + e] = g[e];
#pragma unroll
    for (int q = 0; q < 16; q++) {
        float v = vals[q];
        for (int off = 32; off; off >>= 1) v += __shfl_down(v, off, 64);
        if (lane == 0) atomicAdd(&red[q], v);
    }
    __syncthreads();
    if (n == 0) {
        for (int c = 0; c < 8; c++) cnt8[c] = fmaxf(16.f * red[c], 1.f);
        float l = 0.f;
        for (int e = 0; e < 4; e++) l += (red[8 + e] / 1024.f) * (red[12 + e] / 1024.f);
        loss[0] = 4.f * l;
    }
}

// ---------------- batched QKV projection: grid (256 bm, 8 c); K/V interleaved per token ----
__global__ __launch_bounds__(256) void k_gemm_qkv(const u16* __restrict__ Xb, const u16* __restrict__ Wb,
        const float* __restrict__ ebq, const float* __restrict__ mbq,
        const float* __restrict__ mask8,
        u16* __restrict__ Qb, u16* __restrict__ KVb) {
    __shared__ u16 As[64 * 128];
    __shared__ u16 Bs[128 * 128];
    int tid = threadIdx.x; int bm = blockIdx.x; int c = blockIdx.y;
    int wq = (c < 4) ? c : 20 + (c - 4);
    int wk = (c < 4) ? 4 + c : 24 + (c - 4);
    int wv = (c < 4) ? 8 + c : 28 + (c - 4);
    const u16* Wsl[3] = { Wb + wq * 16384, Wb + wk * 16384, Wb + wv * 16384 };
    const float* bq = (c < 4) ? (ebq + c * 128) : (mbq + (c - 4) * 128);
    const float* maskp = mask8 + c * NTOK;
    bool qact = (maskp[bm * 4] != 0.f) || (maskp[bm * 4 + 1] != 0.f) ||
                (maskp[bm * 4 + 2] != 0.f) || (maskp[bm * 4 + 3] != 0.f);
    u16* Qc  = Qb + (size_t)c * ST;
    u16* KVc = KVb + (size_t)c * STKV;

    const uint4* asrc = (const uint4*)(Xb + (size_t)bm * 8192);
#pragma unroll
    for (int it = 0; it < 4; ++it) {
        int ci = it * 256 + tid;
        uint4 v = asrc[ci];
        int byte = ci * 16; int row = byte >> 8;
        *(uint4*)((char*)As + (byte ^ ((row & 7) << 4))) = v;
    }
    __syncthreads();
    int lane = tid & 63, wid = tid >> 6, lr = lane & 15, lg = lane >> 4;
    short8 a[4];
#pragma unroll
    for (int ks = 0; ks < 4; ++ks) {
        int kk = ks * 64 + lg * 16;
        int arow = wid * 16 + lr;
        a[ks] = *(const short8*)((const char*)As + ((arow * 256 + kk) ^ ((arow & 7) << 4)));
    }
    for (int y = 0; y < 3; ++y) {
        if (y == 0 && !qact) continue;   // Q only read for masked tokens (block-uniform skip)
        const uint4* wsrc = (const uint4*)Wsl[y];
#pragma unroll
        for (int it = 0; it < 8; ++it) {
            int qi = it * 256 + tid;
            uint4 v = wsrc[qi];
            int eo = qi * 8; int row = eo >> 7; int byte = eo * 2;
            *(uint4*)((char*)Bs + (byte ^ ((row & 7) << 4))) = v;
        }
        __syncthreads();
        f32x4 acc[8] = {};
#pragma unroll
        for (int ks = 0; ks < 4; ++ks) {
            int kk = ks * 64 + lg * 16;
#pragma unroll
            for (int nc = 0; nc < 8; ++nc) {
                int brow = nc * 16 + lr;
                short8 b = *(const short8*)((const char*)Bs + ((brow * 256 + kk) ^ ((brow & 7) << 4)));
                acc[nc] = __builtin_amdgcn_mfma_f32_16x16x32_bf16(a[ks], b, acc[nc], 0, 0, 0);
            }
        }
        int row0 = bm * 64 + wid * 16 + lg * 4;
#pragma unroll
        for (int nc = 0; nc < 8; ++nc) {
            int col = nc * 16 + lr;
            float bb = (y == 0) ? bq[col] : 0.f;
#pragma unroll
            for (int r = 0; r < 4; r++) {
                u16 hv = f2bf(acc[nc][r] + bb);
                if (y == 0) Qc[(size_t)(row0 + r) * 128 + col] = hv;
                else KVc[(size_t)(row0 + r) * 256 + (y == 2 ? 128 : 0) + col] = hv;
            }
        }
        __syncthreads();
    }
}

// ---------------- gather attention: 1 thread = (t,h), 16 neighbors; KV interleaved -------
// grid 4096 linear, c = bid&7 (XCD pin); wave-uniform n mask skip. Ob aliases Qb slice.
__global__ __launch_bounds__(256) void k_attn(const u16* Qb, const u16* __restrict__ KVb,
        const float* __restrict__ tkv, const int* __restrict__ idx,
        const float* __restrict__ ebk, const float* __restrict__ ebv,
        const float* __restrict__ mbk, const float* __restrict__ mbv,
        const float* __restrict__ mask8, u16* Ob) {
    int bid = blockIdx.x;
    int c = bid & 7, inner = bid >> 3;     // expert -> XCD pinning (round-robin dispatch)
    int tid = threadIdx.x;
    int gid = inner * 256 + tid;
    int t = gid >> 3, h = gid & 7;
    int n = __builtin_amdgcn_readfirstlane(t >> 4);   // wave spans 8 consecutive t, same n
    int bl = t & 15;
    if (mask8[c * NTOK + n] == 0.f) return;           // wave-uniform skip
    // early vectorized loads of idx/tkv rows (wave-uniform address, cache-broadcast)
    const int4* ip = (const int4*)(idx + n * 16);
    int4 iv0 = ip[0], iv1 = ip[1], iv2 = ip[2], iv3 = ip[3];
    const float4* tp = (const float4*)(tkv + n * 16);
    float4 tv0 = tp[0], tv1 = tp[1], tv2 = tp[2], tv3 = tp[3];
    const u16* Qc = Qb + (size_t)c * ST;
    const u16* KVc = KVb + (size_t)c * STKV;
    u16* Oc = Ob + (size_t)c * ST;
    const float* bk = (c < 4) ? (ebk + c * 128) : (mbk + (c - 4) * 128);
    const float* bv = (c < 4) ? (ebv + c * 128) : (mbv + (c - 4) * 128);
    float qv[16];
    {
        const uint4* qp = (const uint4*)(Qc + (size_t)t * 128 + h * 16);
        uint4 a = qp[0], b = qp[1];
        up2(a.x, qv[0], qv[1]);   up2(a.y, qv[2], qv[3]);
        up2(a.z, qv[4], qv[5]);   up2(a.w, qv[6], qv[7]);
        up2(b.x, qv[8], qv[9]);   up2(b.y, qv[10], qv[11]);
        up2(b.z, qv[12], qv[13]); up2(b.w, qv[14], qv[15]);
    }
    float qb = 0.f;
#pragma unroll
    for (int i = 0; i < 16; i++) qb += qv[i] * bk[h * 16 + i];
    int gsav[16] = { iv0.x, iv0.y, iv0.z, iv0.w, iv1.x, iv1.y, iv1.z, iv1.w,
                     iv2.x, iv2.y, iv2.z, iv2.w, iv3.x, iv3.y, iv3.z, iv3.w };
    float tsav[16] = { tv0.x, tv0.y, tv0.z, tv0.w, tv1.x, tv1.y, tv1.z, tv1.w,
                       tv2.x, tv2.y, tv2.z, tv2.w, tv3.x, tv3.y, tv3.z, tv3.w };
    float scv[16]; float smax = -1e30f;
#pragma unroll 2
    for (int k = 0; k < 16; k++) {
        const uint4* kp = (const uint4*)(KVc + (size_t)(gsav[k] * 16 + bl) * 256 + h * 16);
        uint4 a = kp[0], b = kp[1];
        float d0 = 0.f, d1 = 0.f, lo, hi;
        up2(a.x, lo, hi); d0 = fmaf(lo, qv[0], d0);  d1 = fmaf(hi, qv[1], d1);
        up2(a.y, lo, hi); d0 = fmaf(lo, qv[2], d0);  d1 = fmaf(hi, qv[3], d1);
        up2(a.z, lo, hi); d0 = fmaf(lo, qv[4], d0);  d1 = fmaf(hi, qv[5], d1);
        up2(a.w, lo, hi); d0 = fmaf(lo, qv[6], d0);  d1 = fmaf(hi, qv[7], d1);
        up2(b.x, lo, hi); d0 = fmaf(lo, qv[8], d0);  d1 = fmaf(hi, qv[9], d1);
        up2(b.y, lo, hi); d0 = fmaf(lo, qv[10], d0); d1 = fmaf(hi, qv[11], d1);
        up2(b.z, lo, hi); d0 = fmaf(lo, qv[12], d0); d1 = fmaf(hi, qv[13], d1);
        up2(b.w, lo, hi); d0 = fmaf(lo, qv[14], d0); d1 = fmaf(hi, qv[15], d1);
        float sv = 0.25f * (tsav[k] * (d0 + d1) + qb);   // k = tkv*kx + bk ; 1/sqrt(dh)=0.25
        scv[k] = sv; smax = fmaxf(smax, sv);
    }
    float sum = 0.f;
#pragma unroll
    for (int k = 0; k < 16; k++) { scv[k] = __expf(scv[k] - smax); sum += scv[k]; }
    float inv = 1.f / sum;
    float o[16];
#pragma unroll
    for (int i = 0; i < 16; i++) o[i] = 0.f;
#pragma unroll 2
    for (int k = 0; k < 16; k++) {
        const uint4* vp = (const uint4*)(KVc + (size_t)(gsav[k] * 16 + bl) * 256 + 128 + h * 16);
        uint4 a = vp[0], b = vp[1];
        float cc = scv[k] * inv * tsav[k];
        float lo, hi;
        up2(a.x, lo, hi); o[0] = fmaf(lo, cc, o[0]);   o[1] = fmaf(hi, cc, o[1]);
        up2(a.y, lo, hi); o[2] = fmaf(lo, cc, o[2]);   o[3] = fmaf(hi, cc, o[3]);
        up2(a.z, lo, hi); o[4] = fmaf(lo, cc, o[4]);   o[5] = fmaf(hi, cc, o[5]);
        up2(a.w, lo, hi); o[6] = fmaf(lo, cc, o[6]);   o[7] = fmaf(hi, cc, o[7]);
        up2(b.x, lo, hi); o[8] = fmaf(lo, cc, o[8]);   o[9] = fmaf(hi, cc, o[9]);
        up2(b.y, lo, hi); o[10] = fmaf(lo, cc, o[10]); o[11] = fmaf(hi, cc, o[11]);
        up2(b.z, lo, hi); o[12] = fmaf(lo, cc, o[12]); o[13] = fmaf(hi, cc, o[13]);
        up2(b.w, lo, hi); o[14] = fmaf(lo, cc, o[14]); o[15] = fmaf(hi, cc, o[15]);
    }
#pragma unroll
    for (int i = 0; i < 16; i++) o[i] += bv[h * 16 + i];   // sum(attn)=1
    uint4 s0, s1;
    s0.x = pack2(f2bf(o[0]), f2bf(o[1]));  s0.y = pack2(f2bf(o[2]), f2bf(o[3]));
    s0.z = pack2(f2bf(o[4]), f2bf(o[5]));  s0.w = pack2(f2bf(o[6]), f2bf(o[7]));
    s1.x = pack2(f2bf(o[8]), f2bf(o[9]));  s1.y = pack2(f2bf(o[10]), f2bf(o[11]));
    s1.z = pack2(f2bf(o[12]), f2bf(o[13])); s1.w = pack2(f2bf(o[14]), f2bf(o[15]));
    uint4* op = (uint4*)(Oc + (size_t)t * 128 + h * 16);
    op[0] = s0; op[1] = s1;
}

// ---------------- O @ Wo.T + bo with masked BN stats; block skip; bf16 O2: grid (256,8) ----
__global__ __launch_bounds__(256) void k_gemm_o(const u16* __restrict__ Ab, const u16* __restrict__ Wb,
        const float* __restrict__ ebo, const float* __restrict__ mbo,
        u16* __restrict__ O2, const float* __restrict__ mask8,
        float* __restrict__ bnsum, float* __restrict__ bnsq) {
    __shared__ u16 As[64 * 128];
    __shared__ u16 Bs[128 * 128];
    __shared__ float ssum[128], ssq[128];
    int tid = threadIdx.x; int bm = blockIdx.x; int c = blockIdx.y;
    const float* maskp = mask8 + c * NTOK;
    // whole-block skip: all 4 tokens masked out => O2 never consumed, no stats
    if (maskp[bm * 4] == 0.f && maskp[bm * 4 + 1] == 0.f &&
        maskp[bm * 4 + 2] == 0.f && maskp[bm * 4 + 3] == 0.f) return;
    int wo = (c < 4) ? 12 + c : 32 + (c - 4);
    const u16* Wp = Wb + wo * 16384;
    const float* bo = (c < 4) ? (ebo + c * 128) : (mbo + (c - 4) * 128);
    if (tid < 128) { ssum[tid] = 0.f; ssq[tid] = 0.f; }
    const uint4* asrc = (const uint4*)(Ab + (size_t)c * ST + (size_t)bm * 8192);
#pragma unroll
    for (int it = 0; it < 4; ++it) {
        int ci = it * 256 + tid;
        uint4 v = asrc[ci];
        int byte = ci * 16; int row = byte >> 8;
        *(uint4*)((char*)As + (byte ^ ((row & 7) << 4))) = v;
    }
    const uint4* wsrc = (const uint4*)Wp;
#pragma unroll
    for (int it = 0; it < 8; ++it) {
        int qi = it * 256 + tid;
        uint4 v = wsrc[qi];
        int eo = qi * 8; int row = eo >> 7; int byte = eo * 2;
        *(uint4*)((char*)Bs + (byte ^ ((row & 7) << 4))) = v;
    }
    __syncthreads();
    int lane = tid & 63, wid = tid >> 6, lr = lane & 15, lg = lane >> 4;
    f32x4 acc[8] = {};
#pragma unroll
    for (int ks = 0; ks < 4; ++ks) {
        int kk = ks * 64 + lg * 16;
        int arow = wid * 16 + lr;
        short8 a = *(const short8*)((const char*)As + ((arow * 256 + kk) ^ ((arow & 7) << 4)));
#pragma unroll
        for (int nc = 0; nc < 8; ++nc) {
            int brow = nc * 16 + lr;
            short8 b = *(const short8*)((const char*)Bs + ((brow * 256 + kk) ^ ((brow & 7) << 4)));
            acc[nc] = __builtin_amdgcn_mfma_f32_16x16x32_bf16(a, b, acc[nc], 0, 0, 0);
        }
    }
    int nidx = bm * 4 + wid;
    float mk = maskp[nidx];
    int row0 = bm * 64 + wid * 16 + lg * 4;
    u16* O2c = O2 + (size_t)c * ST;
    float ps[8], pq[8];
#pragma unroll
    for (int nc = 0; nc < 8; ++nc) {
        int col = nc * 16 + lr;
        float bb = bo[col];
        float sv = 0.f, qv = 0.f;
#pragma unroll
        for (int r = 0; r < 4; r++) {
            float v = acc[nc][r] + bb;
            if (mk != 0.f) O2c[(size_t)(row0 + r) * 128 + col] = f2bf(v);
            sv += v; qv += v * v;
        }
        ps[nc] = sv * mk; pq[nc] = qv * mk;
    }
#pragma unroll
    for (int nc = 0; nc < 8; ++nc) {
        ps[nc] += __shfl_xor(ps[nc], 16, 64); ps[nc] += __shfl_xor(ps[nc], 32, 64);
        pq[nc] += __shfl_xor(pq[nc], 16, 64); pq[nc] += __shfl_xor(pq[nc], 32, 64);
    }
    if (lane < 16) {
#pragma unroll
        for (int nc = 0; nc < 8; ++nc) {
            atomicAdd(&ssum[nc * 16 + lane], ps[nc]);
            atomicAdd(&ssq[nc * 16 + lane], pq[nc]);
        }
    }
    __syncthreads();
    if (tid < 128) { atomicAdd(&bnsum[c * 128 + tid], ssum[tid]); atomicAdd(&bnsq[c * 128 + tid], ssq[tid]); }
}

// ---------------- fused final GEMM over 8 experts, 512 threads (8 waves): grid 256 ----------
__global__ __launch_bounds__(512) void k_gemm_w1(const u16* __restrict__ O2, const u16* __restrict__ Xb,
        const u16* __restrict__ Wb, const float* __restrict__ eb1, const float* __restrict__ mb2,
        const float* __restrict__ eGamma, const float* __restrict__ mGamma,
        const float* __restrict__ eBeta, const float* __restrict__ mBeta,
        const float* __restrict__ comb8, const float* __restrict__ cnt8,
        const float* __restrict__ bnsum, const float* __restrict__ bnsq,
        float* __restrict__ out) {
    __shared__ u16 As[64 * 128];
    __shared__ u16 Bs[128 * 128];
    __shared__ float scall[8][128], shall[8][128];
    int tid = threadIdx.x; int bm = blockIdx.x;
    // BN scale/shift for all 8 experts
#pragma unroll
    for (int j = 0; j < 2; ++j) {
        int id = j * 512 + tid;
        int c = id >> 7, d = id & 127;
        float cnt = cnt8[c];
        float mean = bnsum[c * 128 + d] / cnt;
        float var = bnsq[c * 128 + d] / cnt - mean * mean;
        float rs = rsqrtf(var + EPSV);
        const float* ga = (c < 4) ? (eGamma + c * 128) : (mGamma + (c - 4) * 128);
        const float* be = (c < 4) ? (eBeta + c * 128) : (mBeta + (c - 4) * 128);
        float gg = ga[d];
        scall[c][d] = rs * gg;
        shall[c][d] = be[d] - mean * rs * gg;
    }
    __syncthreads();
    int lane = tid & 63, wid = tid >> 6, lr = lane & 15, lg = lane >> 4;
    int wm = wid & 3, wn = wid >> 2;        // 4 m-frags x 2 n-halves
    f32x4 acc[4] = {};
    const uint4* xsrc = (const uint4*)(Xb + (size_t)bm * 8192);
    for (int c = 0; c < 8; ++c) {
        float wc4[4];
        wc4[0] = comb8[c * NTOK + bm * 4];     wc4[1] = comb8[c * NTOK + bm * 4 + 1];
        wc4[2] = comb8[c * NTOK + bm * 4 + 2]; wc4[3] = comb8[c * NTOK + bm * 4 + 3];
        if (wc4[0] == 0.f && wc4[1] == 0.f && wc4[2] == 0.f && wc4[3] == 0.f) continue;
        int wsl = (c < 4) ? 16 + c : 36 + (c - 4);
        const u16* Wp = Wb + wsl * 16384;
        const uint4* osrc = (const uint4*)(O2 + (size_t)c * ST + (size_t)bm * 8192);
        // stage A = wc * (BN(O2) + x), bf16
#pragma unroll
        for (int it = 0; it < 2; ++it) {
            int qi = it * 512 + tid;
            int eo = qi * 8; int row = eo >> 7; int cb = eo & 127;
            float wc = wc4[row >> 4];
            uint4 ov = osrc[qi]; uint4 xv = xsrc[qi];
            float olo, ohi, xlo, xhi;
            uint4 hh;
            up2(ov.x, olo, ohi); up2(xv.x, xlo, xhi);
            hh.x = pack2(f2bf((olo * scall[c][cb] + shall[c][cb] + xlo) * wc),
                         f2bf((ohi * scall[c][cb + 1] + shall[c][cb + 1] + xhi) * wc));
            up2(ov.y, olo, ohi); up2(xv.y, xlo, xhi);
            hh.y = pack2(f2bf((olo * scall[c][cb + 2] + shall[c][cb + 2] + xlo) * wc),
                         f2bf((ohi * scall[c][cb + 3] + shall[c][cb + 3] + xhi) * wc));
            up2(ov.z, olo, ohi); up2(xv.z, xlo, xhi);
            hh.z = pack2(f2bf((olo * scall[c][cb + 4] + shall[c][cb + 4] + xlo) * wc),
                         f2bf((ohi * scall[c][cb + 5] + shall[c][cb + 5] + xhi) * wc));
            up2(ov.w, olo, ohi); up2(xv.w, xlo, xhi);
            hh.w = pack2(f2bf((olo * scall[c][cb + 6] + shall[c][cb + 6] + xlo) * wc),
                         f2bf((ohi * scall[c][cb + 7] + shall[c][cb + 7] + xhi) * wc));
            *(uint4*)((char*)As + ((eo * 2) ^ ((row & 7) << 4))) = hh;
        }
        const uint4* wsrc = (const uint4*)Wp;
#pragma unroll
        for (int it = 0; it < 4; ++it) {
            int qi = it * 512 + tid;
            uint4 v = wsrc[qi];
            int eo = qi * 8; int row = eo >> 7; int byte = eo * 2;
            *(uint4*)((char*)Bs + (byte ^ ((row & 7) << 4))) = v;
        }
        __syncthreads();
#pragma unroll
        for (int ks = 0; ks < 4; ++ks) {
            int kk = ks * 64 + lg * 16;
            int arow = wm * 16 + lr;
            short8 a = *(const short8*)((const char*)As + ((arow * 256 + kk) ^ ((arow & 7) << 4)));
#pragma unroll
            for (int nc = 0; nc < 4; ++nc) {
                int brow = wn * 64 + nc * 16 + lr;
                short8 b = *(const short8*)((const char*)Bs + ((brow * 256 + kk) ^ ((brow & 7) << 4)));
                acc[nc] = __builtin_amdgcn_mfma_f32_16x16x32_bf16(a, b, acc[nc], 0, 0, 0);
            }
        }
        __syncthreads();
    }
    // epilogue: add Sum_c wc*b1_c and write out once
    int nidx = bm * 4 + wm;
    int row0 = bm * 64 + wm * 16 + lg * 4;
    float wc8[8];
#pragma unroll
    for (int c = 0; c < 8; ++c) wc8[c] = comb8[c * NTOK + nidx];
#pragma unroll
    for (int nc = 0; nc < 4; ++nc) {
        int col = wn * 64 + nc * 16 + lr;
        float bias = 0.f;
#pragma unroll
        for (int c = 0; c < 8; ++c) {
            const float* b1 = (c < 4) ? (eb1 + c * 128) : (mb2 + (c - 4) * 128);
            bias += wc8[c] * b1[col];
        }
#pragma unroll
        for (int r = 0; r < 4; r++)
            out[(size_t)(row0 + r) * 128 + col] = acc[nc][r] + bias;
    }
}

extern "C" void kernel_launch(void* const* d_in, const int* in_sizes, int n_in,
                              void* d_out, int out_size, void* d_ws, size_t ws_size,
                              hipStream_t stream) {
    (void)in_sizes; (void)n_in; (void)ws_size; (void)out_size;
    const float* x    = (const float*)d_in[0];
    const float* mm   = (const float*)d_in[1];
    const float* tkv  = (const float*)d_in[2];
    const int*   idx  = (const int*)d_in[3];
    const int*   modi = (const int*)d_in[4];
    const float* Wr   = (const float*)d_in[5];
    const float* br   = (const float*)d_in[6];
    const float* eWq = (const float*)d_in[7],  *eWk = (const float*)d_in[8],  *eWv = (const float*)d_in[9];
    const float* eWo = (const float*)d_in[10], *eW1 = (const float*)d_in[11];
    const float* mWq = (const float*)d_in[12], *mWk = (const float*)d_in[13], *mWv = (const float*)d_in[14];
    const float* mWo = (const float*)d_in[15], *mW2 = (const float*)d_in[16];
    const float* ebq = (const float*)d_in[17], *ebk = (const float*)d_in[18], *ebv = (const float*)d_in[19];
    const float* ebo = (const float*)d_in[20], *eBeta = (const float*)d_in[21], *eb1 = (const float*)d_in[22];
    const float* mbq = (const float*)d_in[23], *mbk = (const float*)d_in[24], *mbv = (const float*)d_in[25];
    const float* mbo = (const float*)d_in[26], *mBeta = (const float*)d_in[27], *mb2 = (const float*)d_in[28];
    const float* eGamma = (const float*)d_in[29], *mGamma = (const float*)d_in[30];
    float* out = (float*)d_out;

    char* wsb = (char*)d_ws;
    const size_t MB = 1024 * 1024;
    u16* Xb  = (u16*)wsb;                       // 0..4 MB
    u16* Wb  = (u16*)(wsb + 4 * MB);            // 4..5.3 MB (40 x 16384 bf16)
    u16* Qb  = (u16*)(wsb + 8 * MB);            // 8..40 MB  (attn O in-place)
    u16* KVb = (u16*)(wsb + 40 * MB);           // 40..104 MB (8 x 8MB K|V interleaved)
    u16* O2  = (u16*)(wsb + 104 * MB);          // 104..136 MB (bf16)
    float* logits = (float*)(wsb + 136 * MB);
    float* comb8 = logits + 4096;               // [8][1024]
    float* mask8 = comb8 + 8192;                // [8][1024]
    float* cnt8  = mask8 + 8192;                // [8]
    float* bnsum = cnt8 + 16;                   // [8][128]
    float* bnsq  = bnsum + 1024;                // [8][128]

    k_prep<<<1360, 256, 0, stream>>>(x, eWq, eWk, eWv, eWo, eW1, mWq, mWk, mWv, mWo, mW2,
                                     mm, Wr, br, Xb, Wb, logits);
    k_route<<<1, 1024, 0, stream>>>(logits, modi, mask8, comb8, cnt8, bnsum, bnsq,
                                    out + (size_t)TT * DD);
    k_gemm_qkv<<<dim3(256, 8), 256, 0, stream>>>(Xb, Wb, ebq, mbq, mask8, Qb, KVb);
    k_attn<<<4096, 256, 0, stream>>>(Qb, KVb, tkv, idx, ebk, ebv, mbk, mbv, mask8, Qb);
    k_gemm_o<<<dim3(256, 8), 256, 0, stream>>>(Qb, Wb, ebo, mbo, O2, mask8, bnsum, bnsq);
    k_gemm_w1<<<256, 512, 0, stream>>>(O2, Xb, Wb, eb1, mb2, eGamma, mGamma, eBeta, mBeta,
                                       comb8, cnt8, bnsum, bnsq, out);
}